// Round 1
// baseline (663.705 us; speedup 1.0000x reference)
//
#include <hip/hip_runtime.h>
#include <hip/hip_bf16.h>

// Problem constants (match reference setup_inputs)
#define NU 100000
#define NI 200000
#define NB 50000
#define D  64

// Concatenated CSR row-space: 5 graph directions
#define B0 0
#define B1 (NU)
#define B2 (NU + NI)
#define B3 (2 * NU + NI)
#define B4 (2 * NU + NI + NB)
#define RTOT (2 * NU + NI + 2 * NB)   // 500000 rows total

// Bucketing for the two-phase edge sort
#define BKT_SHIFT 12
#define ROWS_PER_BKT 4096
#define NBKT ((RTOT + ROWS_PER_BKT - 1) / ROWS_PER_BKT)   // 123
#define TILE 4096
#define EPT (TILE / 256)

// Degree-permutation bins: 5 segments x 64 degree bins
#define PBINS 64
#define PTOT (5 * PBINS)

typedef unsigned short ushort_t;

// ======================= bf16 helpers =======================

__device__ __forceinline__ unsigned f2bf(float f) {
    unsigned u = __float_as_uint(f);
    return (u + 0x7FFFu + ((u >> 16) & 1u)) >> 16;   // RNE
}

__device__ __forceinline__ uint4 pack8(const float* a) {
    uint4 o;
    o.x = f2bf(a[0]) | (f2bf(a[1]) << 16);
    o.y = f2bf(a[2]) | (f2bf(a[3]) << 16);
    o.z = f2bf(a[4]) | (f2bf(a[5]) << 16);
    o.w = f2bf(a[6]) | (f2bf(a[7]) << 16);
    return o;
}

__device__ __forceinline__ void addbf8(uint4 v, float* a) {
    a[0] += __uint_as_float(v.x << 16);
    a[1] += __uint_as_float(v.x & 0xFFFF0000u);
    a[2] += __uint_as_float(v.y << 16);
    a[3] += __uint_as_float(v.y & 0xFFFF0000u);
    a[4] += __uint_as_float(v.z << 16);
    a[5] += __uint_as_float(v.z & 0xFFFF0000u);
    a[6] += __uint_as_float(v.w << 16);
    a[7] += __uint_as_float(v.w & 0xFFFF0000u);
}

// f32 tables -> bf16 tables (one fused launch; 8 elems/thread)
__global__ void cvt_all_k(const float* __restrict__ U, const float* __restrict__ I,
                          const float* __restrict__ Bf,
                          ushort_t* __restrict__ Ubh, ushort_t* __restrict__ Ibh,
                          ushort_t* __restrict__ Bbh) {
    int t = blockIdx.x * blockDim.x + threadIdx.x;
    const int nU = NU * D / 8, nI = NI * D / 8, nB = NB * D / 8;
    const float* s; ushort_t* d;
    if (t < nU)           { s = U;  d = Ubh; }
    else if (t < nU + nI) { s = I;  d = Ibh; t -= nU; }
    else if (t < nU + nI + nB) { s = Bf; d = Bbh; t -= nU + nI; }
    else return;
    const float4 f0 = *reinterpret_cast<const float4*>(s + (size_t)t * 8);
    const float4 f1 = *reinterpret_cast<const float4*>(s + (size_t)t * 8 + 4);
    float a[8] = {f0.x, f0.y, f0.z, f0.w, f1.x, f1.y, f1.z, f1.w};
    *reinterpret_cast<uint4*>(d + (size_t)t * 8) = pack8(a);
}

// ======================= CSR build =======================

__global__ void hist_all_k(int* __restrict__ deg,
                           const int* __restrict__ ui_row, const int* __restrict__ ui_col,
                           const int* __restrict__ ub_row, const int* __restrict__ ub_col,
                           const int* __restrict__ bi_row,
                           int E_UI, int E_UB, int E_BI) {
    int i = blockIdx.x * blockDim.x + threadIdx.x;
    const int* p; int off;
    if (i < E_UI)                     { p = ui_row; off = B0; }
    else if (i < 2 * E_UI)            { p = ui_col; off = B1; i -= E_UI; }
    else if (i < 2 * E_UI + E_UB)     { p = ub_row; off = B2; i -= 2 * E_UI; }
    else if (i < 2 * E_UI + 2 * E_UB) { p = ub_col; off = B3; i -= 2 * E_UI + E_UB; }
    else if (i < 2 * E_UI + 2 * E_UB + E_BI) { p = bi_row; off = B4; i -= 2 * E_UI + 2 * E_UB; }
    else return;
    atomicAdd(&deg[off + p[i]], 1);
}

__global__ void scan_blocksum_k(const int* __restrict__ deg, int* __restrict__ blockSums, int n) {
    int tid = threadIdx.x;
    int base = blockIdx.x * 2048 + tid * 8;
    int sum = 0;
#pragma unroll
    for (int k = 0; k < 8; k++) {
        int idx = base + k;
        if (idx < n) sum += deg[idx];
    }
#pragma unroll
    for (int off = 32; off; off >>= 1) sum += __shfl_down(sum, off, 64);
    __shared__ int ws[4];
    if ((tid & 63) == 0) ws[tid >> 6] = sum;
    __syncthreads();
    if (tid == 0) blockSums[blockIdx.x] = ws[0] + ws[1] + ws[2] + ws[3];
}

__global__ void scan_offsets_k(int* __restrict__ blockSums, int* __restrict__ rowptr,
                               int numBlocks, int n) {
    int lane = threadIdx.x;  // 64 threads
    int nchunk = (numBlocks + 63) / 64;
    int idx0 = lane * nchunk;
    int vals[8];
    int s = 0;
#pragma unroll 4
    for (int k = 0; k < nchunk; k++) {
        int id = idx0 + k;
        vals[k] = (id < numBlocks) ? blockSums[id] : 0;
        s += vals[k];
    }
    int x = s;
#pragma unroll
    for (int off = 1; off < 64; off <<= 1) {
        int y = __shfl_up(x, off, 64);
        if (lane >= off) x += y;
    }
    int excl = x - s;
#pragma unroll 4
    for (int k = 0; k < nchunk; k++) {
        int id = idx0 + k;
        if (id < numBlocks) blockSums[id] = excl;
        excl += vals[k];
    }
    if (lane == 63) rowptr[n] = x;
}

__global__ void scan_write_k(const int* __restrict__ deg, const int* __restrict__ blockSums,
                             int* __restrict__ rowptr, int n) {
    int tid = threadIdx.x;
    int base = blockIdx.x * 2048 + tid * 8;
    int v[8];
    int sum = 0;
#pragma unroll
    for (int k = 0; k < 8; k++) {
        int idx = base + k;
        int d = (idx < n) ? deg[idx] : 0;
        v[k] = sum;
        sum += d;
    }
    int lane = tid & 63, wave = tid >> 6;
    int x = sum;
#pragma unroll
    for (int off = 1; off < 64; off <<= 1) {
        int y = __shfl_up(x, off, 64);
        if (lane >= off) x += y;
    }
    __shared__ int wsum[4];
    if (lane == 63) wsum[wave] = x;
    __syncthreads();
    int woff = 0;
    for (int w = 0; w < wave; w++) woff += wsum[w];
    int thrOff = blockSums[blockIdx.x] + woff + (x - sum);
#pragma unroll
    for (int k = 0; k < 8; k++) {
        int idx = base + k;
        if (idx < n) rowptr[idx] = thrOff + v[k];
    }
}

__global__ void initgcur_k(const int* __restrict__ rowptr, int* __restrict__ gcur) {
    int b = threadIdx.x;
    if (b < 128) {
        int r = b << BKT_SHIFT;
        gcur[b] = rowptr[r < RTOT ? r : RTOT];
    }
}

// ======================= degree-uniform row permutation =======================
// Counting sort of rows by (segment, min(degree,63)) so each 8-row wave-group in
// the pull stages has uniform trip count (kills exec-mask divergence in pull8).

__device__ __forceinline__ int seg_of_row(int r) {
    return (r < B1) ? 0 : (r < B2) ? 1 : (r < B3) ? 2 : (r < B4) ? 3 : 4;
}

// pass 1: global histogram of (seg, degbin)
__global__ void permhist_k(const int* __restrict__ rowptr, int* __restrict__ gbins) {
    __shared__ int h[PTOT];
    int tid = threadIdx.x;
    for (int i = tid; i < PTOT; i += 256) h[i] = 0;
    __syncthreads();
    int r = blockIdx.x * 256 + tid;
    if (r < RTOT) {
        int d = rowptr[r + 1] - rowptr[r];
        int bin = d < PBINS ? d : PBINS - 1;
        atomicAdd(&h[seg_of_row(r) * PBINS + bin], 1);
    }
    __syncthreads();
    for (int i = tid; i < PTOT; i += 256)
        if (h[i]) atomicAdd(&gbins[i], h[i]);
}

// pass 2: exclusive scan of the 320 bins (seg-major order => segments stay
// contiguous at their natural bases). 64 threads x 5 values.
__global__ void permscan_k(int* __restrict__ gbins) {
    int lane = threadIdx.x;  // 64
    int vals[5];
    int s = 0;
#pragma unroll
    for (int k = 0; k < 5; k++) { vals[k] = gbins[lane * 5 + k]; s += vals[k]; }
    int x = s;
#pragma unroll
    for (int off = 1; off < 64; off <<= 1) {
        int y = __shfl_up(x, off, 64);
        if (lane >= off) x += y;
    }
    int excl = x - s;
#pragma unroll
    for (int k = 0; k < 5; k++) { gbins[lane * 5 + k] = excl; excl += vals[k]; }
}

// pass 3: two-phase scatter (block-local count -> reserve global base -> place)
__global__ __launch_bounds__(256) void permscat_k(const int* __restrict__ rowptr,
                                                  int* __restrict__ gbins,
                                                  int* __restrict__ perm) {
    __shared__ int h[PTOT], bs[PTOT], c2[PTOT];
    int tid = threadIdx.x;
    for (int i = tid; i < PTOT; i += 256) { h[i] = 0; c2[i] = 0; }
    __syncthreads();
    int r0 = blockIdx.x * 2048;
    int sb[8];
#pragma unroll
    for (int k = 0; k < 8; k++) {
        int r = r0 + k * 256 + tid;
        if (r < RTOT) {
            int d = rowptr[r + 1] - rowptr[r];
            int bin = d < PBINS ? d : PBINS - 1;
            sb[k] = seg_of_row(r) * PBINS + bin;
            atomicAdd(&h[sb[k]], 1);
        } else sb[k] = -1;
    }
    __syncthreads();
    for (int i = tid; i < PTOT; i += 256)
        if (h[i]) bs[i] = atomicAdd(&gbins[i], h[i]);
    __syncthreads();
#pragma unroll
    for (int k = 0; k < 8; k++) {
        if (sb[k] >= 0) {
            int r = r0 + k * 256 + tid;
            int loc = atomicAdd(&c2[sb[k]], 1);
            perm[bs[sb[k]] + loc] = r;
        }
    }
}

// ======================= edge binning =======================

__device__ __forceinline__ void decode_edge(int i,
        const int* __restrict__ ui_row, const int* __restrict__ ui_col,
        const int* __restrict__ ub_row, const int* __restrict__ ub_col,
        const int* __restrict__ bi_row, const int* __restrict__ bi_col,
        int E_UI, int E_UB, int E_BI, int& gdst, int& src) {
    if (i < E_UI)                     { gdst = B0 + ui_row[i]; src = ui_col[i]; }
    else if (i < 2 * E_UI)            { int j = i - E_UI; gdst = B1 + ui_col[j]; src = ui_row[j]; }
    else if (i < 2 * E_UI + E_UB)     { int j = i - 2 * E_UI; gdst = B2 + ub_row[j]; src = ub_col[j]; }
    else if (i < 2 * E_UI + 2 * E_UB) { int j = i - 2 * E_UI - E_UB; gdst = B3 + ub_col[j]; src = ub_row[j]; }
    else                              { int j = i - 2 * E_UI - 2 * E_UB; gdst = B4 + bi_row[j]; src = bi_col[j]; }
}

// Phase A: tile-local counting sort by coarse bucket; bbuf entry: (src<<12)|(gdst&4095)
__global__ __launch_bounds__(256) void binA_k(
        const int* __restrict__ ui_row, const int* __restrict__ ui_col,
        const int* __restrict__ ub_row, const int* __restrict__ ub_col,
        const int* __restrict__ bi_row, const int* __restrict__ bi_col,
        int E_UI, int E_UB, int E_BI, int ETOT,
        int* __restrict__ gcur, int* __restrict__ bbuf) {
    __shared__ int hist[NBKT], runStart[NBKT], gbase[NBKT], cnt2[NBKT];
    __shared__ int ord[TILE];
    __shared__ int gpos[TILE];
    int tid = threadIdx.x;
    for (int b = tid; b < NBKT; b += 256) { hist[b] = 0; cnt2[b] = 0; }
    __syncthreads();
    int base = blockIdx.x * TILE;
#pragma unroll
    for (int k = 0; k < EPT; k++) {
        int i = base + k * 256 + tid;
        if (i < ETOT) {
            int gdst, src;
            decode_edge(i, ui_row, ui_col, ub_row, ub_col, bi_row, bi_col,
                        E_UI, E_UB, E_BI, gdst, src);
            atomicAdd(&hist[gdst >> BKT_SHIFT], 1);
        }
    }
    __syncthreads();
    if (tid == 0) {
        int run = 0;
        for (int b = 0; b < NBKT; b++) { runStart[b] = run; run += hist[b]; }
    }
    __syncthreads();
    if (tid < NBKT && hist[tid] > 0) gbase[tid] = atomicAdd(&gcur[tid], hist[tid]);
    __syncthreads();
#pragma unroll
    for (int k = 0; k < EPT; k++) {
        int i = base + k * 256 + tid;
        if (i < ETOT) {
            int gdst, src;
            decode_edge(i, ui_row, ui_col, ub_row, ub_col, bi_row, bi_col,
                        E_UI, E_UB, E_BI, gdst, src);
            int b = gdst >> BKT_SHIFT;
            int loc = runStart[b] + atomicAdd(&cnt2[b], 1);
            ord[loc] = (src << BKT_SHIFT) | (gdst & (ROWS_PER_BKT - 1));
            gpos[loc] = gbase[b] + (loc - runStart[b]);
        }
    }
    __syncthreads();
    int tcnt = runStart[NBKT - 1] + hist[NBKT - 1];
    for (int i = tid; i < tcnt; i += 256) bbuf[gpos[i]] = ord[i];
}

// Phase B: per-bucket row placement; ebuf entry = src byte offset for bf16 rows (src*128)
__global__ __launch_bounds__(1024) void binB_k(const int* __restrict__ rowptr,
                                               const int* __restrict__ bbuf,
                                               int* __restrict__ ebuf) {
    __shared__ int lcur[ROWS_PER_BKT];
    int bkt = blockIdx.x;
    int rbase = bkt << BKT_SHIFT;
    int rend = rbase + ROWS_PER_BKT;
    if (rend > RTOT) rend = RTOT;
    int nrows = rend - rbase;
    for (int r = threadIdx.x; r < nrows; r += 1024) lcur[r] = rowptr[rbase + r];
    __syncthreads();
    int s = rowptr[rbase], e = rowptr[rend];
    for (int i = s + (int)threadIdx.x; i < e; i += 1024) {
        int entry = bbuf[i];
        int r = entry & (ROWS_PER_BKT - 1);
        int pos = atomicAdd(&lcur[r], 1);
        ebuf[pos] = (entry >> BKT_SHIFT) << 7;
    }
}

// ======================= pull machinery (bf16, 8 lanes/row) =======================
// wave = 8 rows; lane l: group = l>>3 (row), q = (l&7)*16B (8 dims as bf16x8).
// Rows are visited in degree-sorted (perm) order so all 8 groups of a wave have
// (nearly) identical trip counts.

__device__ __forceinline__ void pull8(int s, int e, const int* __restrict__ ebuf,
                                      const char* __restrict__ baseq, float* a) {
    int j = s;
    for (; j + 3 < e; j += 4) {
        int c0 = ebuf[j], c1 = ebuf[j + 1], c2 = ebuf[j + 2], c3 = ebuf[j + 3];
        uint4 v0 = *reinterpret_cast<const uint4*>(baseq + c0);
        uint4 v1 = *reinterpret_cast<const uint4*>(baseq + c1);
        uint4 v2 = *reinterpret_cast<const uint4*>(baseq + c2);
        uint4 v3 = *reinterpret_cast<const uint4*>(baseq + c3);
        addbf8(v0, a); addbf8(v1, a); addbf8(v2, a); addbf8(v3, a);
    }
    for (; j < e; ++j) {
        uint4 v = *reinterpret_cast<const uint4*>(baseq + ebuf[j]);
        addbf8(v, a);
    }
}

__device__ __forceinline__ float rowsum8(float s) {
    s += __shfl_xor(s, 1, 64);
    s += __shfl_xor(s, 2, 64);
    s += __shfl_xor(s, 4, 64);
    return s;
}

// stage1: all four layer-1 pulls fused; bf16 in, bf16 out, no cross-lane needed
__global__ void stage1_k(const int* __restrict__ rowptr, const int* __restrict__ ebuf,
                         const int* __restrict__ perm,
                         const ushort_t* __restrict__ Ubh, const ushort_t* __restrict__ Ibh,
                         const ushort_t* __restrict__ Bbh,
                         ushort_t* __restrict__ f1u_ui, ushort_t* __restrict__ f1i_ui,
                         ushort_t* __restrict__ f1u_ub, ushort_t* __restrict__ f1b_ub) {
    int gr0 = blockIdx.x * 32 + (threadIdx.x >> 3);
    if (gr0 >= B4) return;
    int gr = perm[gr0];
    int q = (threadIdx.x & 7) << 4;
    const ushort_t* src; ushort_t* dst; int row;
    if (gr < B1)      { src = Ibh; dst = f1u_ui; row = gr; }
    else if (gr < B2) { src = Ubh; dst = f1i_ui; row = gr - B1; }
    else if (gr < B3) { src = Bbh; dst = f1u_ub; row = gr - B2; }
    else              { src = Ubh; dst = f1b_ub; row = gr - B3; }
    int s = rowptr[gr], e = rowptr[gr + 1];
    float a[8] = {0, 0, 0, 0, 0, 0, 0, 0};
    pull8(s, e, ebuf, (const char*)src + q, a);
    *reinterpret_cast<uint4*>((char*)dst + (size_t)row * 128 + q) = pack8(a);
}

// finalize: out(f32) = base + l2norm(self) + l2norm(acc)
__device__ __forceinline__ void fin8_f32(const float* a, const ushort_t* selfbh,
                                         const float* basef, float* out, int row, int l) {
    int q = l << 4;
    uint4 sv = *reinterpret_cast<const uint4*>((const char*)selfbh + (size_t)row * 128 + q);
    float v[8] = {0, 0, 0, 0, 0, 0, 0, 0};
    addbf8(sv, v);
    float s1 = 0.f, s2 = 0.f;
#pragma unroll
    for (int k = 0; k < 8; k++) { s1 = fmaf(v[k], v[k], s1); s2 = fmaf(a[k], a[k], s2); }
    s1 = rowsum8(s1);
    s2 = rowsum8(s2);
    float i1 = 1.0f / fmaxf(sqrtf(s1), 1e-12f);
    float i2 = 1.0f / fmaxf(sqrtf(s2), 1e-12f);
    const float4 b0 = *reinterpret_cast<const float4*>(basef + (size_t)row * D + l * 8);
    const float4 b1 = *reinterpret_cast<const float4*>(basef + (size_t)row * D + l * 8 + 4);
    float4 o0, o1;
    o0.x = b0.x + v[0] * i1 + a[0] * i2;
    o0.y = b0.y + v[1] * i1 + a[1] * i2;
    o0.z = b0.z + v[2] * i1 + a[2] * i2;
    o0.w = b0.w + v[3] * i1 + a[3] * i2;
    o1.x = b1.x + v[4] * i1 + a[4] * i2;
    o1.y = b1.y + v[5] * i1 + a[5] * i2;
    o1.z = b1.z + v[6] * i1 + a[6] * i2;
    o1.w = b1.w + v[7] * i1 + a[7] * i2;
    *reinterpret_cast<float4*>(out + (size_t)row * 128 + l * 8) = o0;
    *reinterpret_cast<float4*>(out + (size_t)row * 128 + l * 8 + 4) = o1;
}

// stage2a: ui-user, ub-user, ub-bundle finalize fused -> f32 outputs
__global__ void stage2a_k(const int* __restrict__ rowptr, const int* __restrict__ ebuf,
                          const int* __restrict__ perm,
                          const float* __restrict__ U, const float* __restrict__ Bf,
                          const ushort_t* __restrict__ f1u_ui, const ushort_t* __restrict__ f1i_ui,
                          const ushort_t* __restrict__ f1u_ub, const ushort_t* __restrict__ f1b_ub,
                          float* __restrict__ outU, float* __restrict__ outB) {
    int t = blockIdx.x * 32 + (threadIdx.x >> 3);
    if (t >= 2 * NU + NB) return;
    int l = threadIdx.x & 7;
    int cr, row; const ushort_t* src; const ushort_t* self; const float* basef; float* out;
    if (t < NU)          { cr = perm[t];               src = f1i_ui; self = f1u_ui; basef = U;  out = outU;      row = cr; }
    else if (t < 2 * NU) { cr = perm[B2 + t - NU];     src = f1b_ub; self = f1u_ub; basef = U;  out = outU + 64; row = cr - B2; }
    else                 { cr = perm[B3 + t - 2 * NU]; src = f1u_ub; self = f1b_ub; basef = Bf; out = outB + 64; row = cr - B3; }
    int q = l << 4;
    int s = rowptr[cr], e = rowptr[cr + 1];
    float a[8] = {0, 0, 0, 0, 0, 0, 0, 0};
    pull8(s, e, ebuf, (const char*)src + q, a);
    fin8_f32(a, self, basef, out, row, l);
}

// stage2b: ui-item finalize; acc_i written IN PLACE (bf16) over f1i_ui
__global__ void stage2b_k(const int* __restrict__ rowptr, const int* __restrict__ ebuf,
                          const int* __restrict__ perm,
                          const float* __restrict__ I, const ushort_t* __restrict__ f1u_ui,
                          ushort_t* __restrict__ f1i_ui) {
    int t = blockIdx.x * 32 + (threadIdx.x >> 3);
    if (t >= NI) return;
    int l = threadIdx.x & 7;
    int q = l << 4;
    int cr = perm[B1 + t];
    int row = cr - B1;
    int s = rowptr[cr], e = rowptr[cr + 1];
    float a[8] = {0, 0, 0, 0, 0, 0, 0, 0};
    pull8(s, e, ebuf, (const char*)f1u_ui + q, a);
    uint4 sv = *reinterpret_cast<const uint4*>((const char*)f1i_ui + (size_t)row * 128 + q);
    float v[8] = {0, 0, 0, 0, 0, 0, 0, 0};
    addbf8(sv, v);
    float s1 = 0.f, s2 = 0.f;
#pragma unroll
    for (int k = 0; k < 8; k++) { s1 = fmaf(v[k], v[k], s1); s2 = fmaf(a[k], a[k], s2); }
    s1 = rowsum8(s1);
    s2 = rowsum8(s2);
    float i1 = 1.0f / fmaxf(sqrtf(s1), 1e-12f);
    float i2 = 1.0f / fmaxf(sqrtf(s2), 1e-12f);
    const float4 b0 = *reinterpret_cast<const float4*>(I + (size_t)row * D + l * 8);
    const float4 b1 = *reinterpret_cast<const float4*>(I + (size_t)row * D + l * 8 + 4);
    float o[8];
    o[0] = b0.x + v[0] * i1 + a[0] * i2;
    o[1] = b0.y + v[1] * i1 + a[1] * i2;
    o[2] = b0.z + v[2] * i1 + a[2] * i2;
    o[3] = b0.w + v[3] * i1 + a[3] * i2;
    o[4] = b1.x + v[4] * i1 + a[4] * i2;
    o[5] = b1.y + v[5] * i1 + a[5] * i2;
    o[6] = b1.z + v[6] * i1 + a[6] * i2;
    o[7] = b1.w + v[7] * i1 + a[7] * i2;
    *reinterpret_cast<uint4*>((char*)f1i_ui + (size_t)row * 128 + q) = pack8(o);
}

// stage3: weighted bi aggregation from bf16 acc_i -> outB[:,0:64] (f32)
__global__ void stage3_k(const int* __restrict__ rowptr, const int* __restrict__ ebuf,
                         const int* __restrict__ perm,
                         const ushort_t* __restrict__ acc_i, float* __restrict__ outB) {
    int t = blockIdx.x * 32 + (threadIdx.x >> 3);
    if (t >= NB) return;
    int l = threadIdx.x & 7;
    int q = l << 4;
    int cr = perm[B4 + t];
    int row = cr - B4;
    int s = rowptr[cr], e = rowptr[cr + 1];
    float a[8] = {0, 0, 0, 0, 0, 0, 0, 0};
    pull8(s, e, ebuf, (const char*)acc_i + q, a);
    float w = 1.0f / ((float)(e - s) + 1e-8f);
    float4 o0 = {a[0] * w, a[1] * w, a[2] * w, a[3] * w};
    float4 o1 = {a[4] * w, a[5] * w, a[6] * w, a[7] * w};
    *reinterpret_cast<float4*>(outB + (size_t)row * 128 + l * 8) = o0;
    *reinterpret_cast<float4*>(outB + (size_t)row * 128 + l * 8 + 4) = o1;
}

extern "C" void kernel_launch(void* const* d_in, const int* in_sizes, int n_in,
                              void* d_out, int out_size, void* d_ws, size_t ws_size,
                              hipStream_t stream) {
    const float* U = (const float*)d_in[0];
    const float* I = (const float*)d_in[1];
    const float* B = (const float*)d_in[2];
    const int* ui_row = (const int*)d_in[3];
    const int* ui_col = (const int*)d_in[4];
    const int* ub_row = (const int*)d_in[5];
    const int* ub_col = (const int*)d_in[6];
    const int* bi_row = (const int*)d_in[7];
    const int* bi_col = (const int*)d_in[8];
    const int E_UI = in_sizes[3], E_UB = in_sizes[5], E_BI = in_sizes[7];
    const int ETOT = 2 * E_UI + 2 * E_UB + E_BI;

    // workspace layout (~144 MB): bf16 tables + bf16 intermediates + CSR + perm
    ushort_t* Ubh    = (ushort_t*)d_ws;                 // NU*D
    ushort_t* Ibh    = Ubh + (size_t)NU * D;            // NI*D
    ushort_t* Bbh    = Ibh + (size_t)NI * D;            // NB*D
    ushort_t* f1u_ui = Bbh + (size_t)NB * D;            // NU*D
    ushort_t* f1i_ui = f1u_ui + (size_t)NU * D;         // NI*D (becomes acc_i)
    ushort_t* f1u_ub = f1i_ui + (size_t)NI * D;         // NU*D
    ushort_t* f1b_ub = f1u_ub + (size_t)NU * D;         // NB*D
    int* deg       = (int*)(f1b_ub + (size_t)NB * D);   // RTOT
    int* rowptr    = deg + RTOT;                        // RTOT+1
    int* blockSums = rowptr + (RTOT + 1);               // 256
    int* gcur      = blockSums + 256;                   // 128
    int* ebuf      = gcur + 128;                        // ETOT
    int* bbuf      = ebuf + ETOT;                       // ETOT
    int* perm      = bbuf + ETOT;                       // RTOT
    int* gbins     = perm + RTOT;                       // PTOT (320)

    float* outU = (float*)d_out;            // NU x 128 (IL_u | BL_u)
    float* outB = outU + (size_t)NU * 128;  // NB x 128 (IL_b | BL_b)

    const int T = 256;
    const int SB = (RTOT + 2047) / 2048;
    const int NCVT = (NU + NI + NB) * D / 8;

    // ---- bf16 table conversion ----
    cvt_all_k<<<(NCVT + T - 1) / T, T, 0, stream>>>(U, I, B, Ubh, Ibh, Bbh);

    // ---- CSR build ----
    hipMemsetAsync(deg, 0, RTOT * sizeof(int), stream);
    hist_all_k<<<(ETOT + T - 1) / T, T, 0, stream>>>(deg, ui_row, ui_col, ub_row, ub_col,
                                                     bi_row, E_UI, E_UB, E_BI);
    scan_blocksum_k<<<SB, T, 0, stream>>>(deg, blockSums, RTOT);
    scan_offsets_k<<<1, 64, 0, stream>>>(blockSums, rowptr, SB, RTOT);
    scan_write_k<<<SB, T, 0, stream>>>(deg, blockSums, rowptr, RTOT);
    initgcur_k<<<1, 128, 0, stream>>>(rowptr, gcur);

    // ---- degree-uniform row permutation (removes pull-loop divergence) ----
    hipMemsetAsync(gbins, 0, PTOT * sizeof(int), stream);
    permhist_k<<<(RTOT + 255) / 256, 256, 0, stream>>>(rowptr, gbins);
    permscan_k<<<1, 64, 0, stream>>>(gbins);
    permscat_k<<<(RTOT + 2047) / 2048, 256, 0, stream>>>(rowptr, gbins, perm);

    // ---- edge binning ----
    binA_k<<<(ETOT + TILE - 1) / TILE, 256, 0, stream>>>(ui_row, ui_col, ub_row, ub_col,
                                                         bi_row, bi_col, E_UI, E_UB, E_BI,
                                                         ETOT, gcur, bbuf);
    binB_k<<<NBKT, 1024, 0, stream>>>(rowptr, bbuf, ebuf);

    // ---- stage1: all four layer-1 pulls ----
    stage1_k<<<(B4 + 31) / 32, T, 0, stream>>>(rowptr, ebuf, perm, Ubh, Ibh, Bbh,
                                               f1u_ui, f1i_ui, f1u_ub, f1b_ub);
    // ---- stage2a: ui-user, ub-user, ub-bundle finalize ----
    stage2a_k<<<(2 * NU + NB + 31) / 32, T, 0, stream>>>(rowptr, ebuf, perm, U, B,
                                                         f1u_ui, f1i_ui, f1u_ub, f1b_ub,
                                                         outU, outB);
    // ---- stage2b: ui-item finalize (in-place bf16 acc_i) ----
    stage2b_k<<<(NI + 31) / 32, T, 0, stream>>>(rowptr, ebuf, perm, I, f1u_ui, f1i_ui);
    // ---- stage3: weighted bi aggregation ----
    stage3_k<<<(NB + 31) / 32, T, 0, stream>>>(rowptr, ebuf, perm, f1i_ui, outB);
}

// Round 8
// 532.173 us; speedup vs baseline: 1.2472x; 1.2472x over previous
//
#include <hip/hip_runtime.h>
#include <hip/hip_bf16.h>

// Problem constants (match reference setup_inputs)
#define NU 100000
#define NI 200000
#define NB 50000
#define D  64

// Concatenated CSR row-space: 5 graph directions
#define B0 0
#define B1 (NU)
#define B2 (NU + NI)
#define B3 (2 * NU + NI)
#define B4 (2 * NU + NI + NB)
#define RTOT (2 * NU + NI + 2 * NB)   // 500000 rows total

// Bucketing for the two-phase edge sort
#define BKT_SHIFT 12
#define ROWS_PER_BKT 4096
#define NBKT ((RTOT + ROWS_PER_BKT - 1) / ROWS_PER_BKT)   // 123
#define TILE 4096
#define EPT (TILE / 256)

// Degree-permutation bins: 5 segments x 64 degree bins
#define PBINS 64
#define PTOT (5 * PBINS)

typedef unsigned short ushort_t;

// ======================= bf16 helpers =======================

__device__ __forceinline__ unsigned f2bf(float f) {
    unsigned u = __float_as_uint(f);
    return (u + 0x7FFFu + ((u >> 16) & 1u)) >> 16;   // RNE
}

__device__ __forceinline__ uint4 pack8(const float* a) {
    uint4 o;
    o.x = f2bf(a[0]) | (f2bf(a[1]) << 16);
    o.y = f2bf(a[2]) | (f2bf(a[3]) << 16);
    o.z = f2bf(a[4]) | (f2bf(a[5]) << 16);
    o.w = f2bf(a[6]) | (f2bf(a[7]) << 16);
    return o;
}

__device__ __forceinline__ void addbf8(uint4 v, float* a) {
    a[0] += __uint_as_float(v.x << 16);
    a[1] += __uint_as_float(v.x & 0xFFFF0000u);
    a[2] += __uint_as_float(v.y << 16);
    a[3] += __uint_as_float(v.y & 0xFFFF0000u);
    a[4] += __uint_as_float(v.z << 16);
    a[5] += __uint_as_float(v.z & 0xFFFF0000u);
    a[6] += __uint_as_float(v.w << 16);
    a[7] += __uint_as_float(v.w & 0xFFFF0000u);
}

// f32 tables -> bf16 tables (one fused launch; 8 elems/thread)
__global__ void cvt_all_k(const float* __restrict__ U, const float* __restrict__ I,
                          const float* __restrict__ Bf,
                          ushort_t* __restrict__ Ubh, ushort_t* __restrict__ Ibh,
                          ushort_t* __restrict__ Bbh) {
    int t = blockIdx.x * blockDim.x + threadIdx.x;
    const int nU = NU * D / 8, nI = NI * D / 8, nB = NB * D / 8;
    const float* s; ushort_t* d;
    if (t < nU)           { s = U;  d = Ubh; }
    else if (t < nU + nI) { s = I;  d = Ibh; t -= nU; }
    else if (t < nU + nI + nB) { s = Bf; d = Bbh; t -= nU + nI; }
    else return;
    const float4 f0 = *reinterpret_cast<const float4*>(s + (size_t)t * 8);
    const float4 f1 = *reinterpret_cast<const float4*>(s + (size_t)t * 8 + 4);
    float a[8] = {f0.x, f0.y, f0.z, f0.w, f1.x, f1.y, f1.z, f1.w};
    *reinterpret_cast<uint4*>(d + (size_t)t * 8) = pack8(a);
}

// ======================= bucket histogram (replaces 500K-bin global hist) ===
// 123 coarse buckets; LDS-staged so global atomics drop to NBKT per block.

__global__ __launch_bounds__(256) void bhist_k(
        const int* __restrict__ ui_row, const int* __restrict__ ui_col,
        const int* __restrict__ ub_row, const int* __restrict__ ub_col,
        const int* __restrict__ bi_row,
        int E_UI, int E_UB, int E_BI, int ETOT, int* __restrict__ gbase) {
    __shared__ int h[NBKT];
    int tid = threadIdx.x;
    for (int b = tid; b < NBKT; b += 256) h[b] = 0;
    __syncthreads();
    for (int i = blockIdx.x * 256 + tid; i < ETOT; i += gridDim.x * 256) {
        int gdst;
        if (i < E_UI)                     gdst = B0 + ui_row[i];
        else if (i < 2 * E_UI)            gdst = B1 + ui_col[i - E_UI];
        else if (i < 2 * E_UI + E_UB)     gdst = B2 + ub_row[i - 2 * E_UI];
        else if (i < 2 * E_UI + 2 * E_UB) gdst = B3 + ub_col[i - 2 * E_UI - E_UB];
        else                              gdst = B4 + bi_row[i - 2 * E_UI - 2 * E_UB];
        atomicAdd(&h[gdst >> BKT_SHIFT], 1);
    }
    __syncthreads();
    for (int b = tid; b < NBKT; b += 256)
        if (h[b]) atomicAdd(&gbase[b], h[b]);
}

// one-wave exclusive scan of the 123 bucket counts -> gbase (bases), gcur copy.
// Also sets gbase[NBKT] = ETOT and rowptr[RTOT] = ETOT.
__global__ void bscan_k(int* __restrict__ gbase, int* __restrict__ gcur,
                        int* __restrict__ rowptr) {
    int lane = threadIdx.x;  // 64
    int i0 = lane * 2, i1 = lane * 2 + 1;
    int v0 = (i0 < NBKT) ? gbase[i0] : 0;
    int v1 = (i1 < NBKT) ? gbase[i1] : 0;
    int s = v0 + v1;
    int x = s;
#pragma unroll
    for (int off = 1; off < 64; off <<= 1) {
        int y = __shfl_up(x, off, 64);
        if (lane >= off) x += y;
    }
    int e0 = x - s;          // exclusive at i0
    int e1 = e0 + v0;        // exclusive at i1
    if (i0 <= NBKT) gbase[i0] = e0;
    if (i1 <= NBKT) gbase[i1] = e1;
    if (i0 < NBKT) gcur[i0] = e0;
    if (i1 < NBKT) gcur[i1] = e1;
    if (lane == 63) rowptr[RTOT] = x;   // total == ETOT
}

// ======================= degree-uniform row permutation =======================
// Counting sort of rows by (segment, min(degree,63)) so each 8-row wave-group in
// the pull stages has uniform trip count (kills exec-mask divergence in pull8).

__device__ __forceinline__ int seg_of_row(int r) {
    return (r < B1) ? 0 : (r < B2) ? 1 : (r < B3) ? 2 : (r < B4) ? 3 : 4;
}

// pass 1: global histogram of (seg, degbin)
__global__ void permhist_k(const int* __restrict__ rowptr, int* __restrict__ gbins) {
    __shared__ int h[PTOT];
    int tid = threadIdx.x;
    for (int i = tid; i < PTOT; i += 256) h[i] = 0;
    __syncthreads();
    int r = blockIdx.x * 256 + tid;
    if (r < RTOT) {
        int d = rowptr[r + 1] - rowptr[r];
        int bin = d < PBINS ? d : PBINS - 1;
        atomicAdd(&h[seg_of_row(r) * PBINS + bin], 1);
    }
    __syncthreads();
    for (int i = tid; i < PTOT; i += 256)
        if (h[i]) atomicAdd(&gbins[i], h[i]);
}

// pass 2: exclusive scan of the 320 bins (seg-major order => segments stay
// contiguous at their natural bases). 64 threads x 5 values.
__global__ void permscan_k(int* __restrict__ gbins) {
    int lane = threadIdx.x;  // 64
    int vals[5];
    int s = 0;
#pragma unroll
    for (int k = 0; k < 5; k++) { vals[k] = gbins[lane * 5 + k]; s += vals[k]; }
    int x = s;
#pragma unroll
    for (int off = 1; off < 64; off <<= 1) {
        int y = __shfl_up(x, off, 64);
        if (lane >= off) x += y;
    }
    int excl = x - s;
#pragma unroll
    for (int k = 0; k < 5; k++) { gbins[lane * 5 + k] = excl; excl += vals[k]; }
}

// pass 3: two-phase scatter (block-local count -> reserve global base -> place)
__global__ __launch_bounds__(256) void permscat_k(const int* __restrict__ rowptr,
                                                  int* __restrict__ gbins,
                                                  int* __restrict__ perm) {
    __shared__ int h[PTOT], bs[PTOT], c2[PTOT];
    int tid = threadIdx.x;
    for (int i = tid; i < PTOT; i += 256) { h[i] = 0; c2[i] = 0; }
    __syncthreads();
    int r0 = blockIdx.x * 2048;
    int sb[8];
#pragma unroll
    for (int k = 0; k < 8; k++) {
        int r = r0 + k * 256 + tid;
        if (r < RTOT) {
            int d = rowptr[r + 1] - rowptr[r];
            int bin = d < PBINS ? d : PBINS - 1;
            sb[k] = seg_of_row(r) * PBINS + bin;
            atomicAdd(&h[sb[k]], 1);
        } else sb[k] = -1;
    }
    __syncthreads();
    for (int i = tid; i < PTOT; i += 256)
        if (h[i]) bs[i] = atomicAdd(&gbins[i], h[i]);
    __syncthreads();
#pragma unroll
    for (int k = 0; k < 8; k++) {
        if (sb[k] >= 0) {
            int r = r0 + k * 256 + tid;
            int loc = atomicAdd(&c2[sb[k]], 1);
            perm[bs[sb[k]] + loc] = r;
        }
    }
}

// ======================= edge binning =======================

__device__ __forceinline__ void decode_edge(int i,
        const int* __restrict__ ui_row, const int* __restrict__ ui_col,
        const int* __restrict__ ub_row, const int* __restrict__ ub_col,
        const int* __restrict__ bi_row, const int* __restrict__ bi_col,
        int E_UI, int E_UB, int E_BI, int& gdst, int& src) {
    if (i < E_UI)                     { gdst = B0 + ui_row[i]; src = ui_col[i]; }
    else if (i < 2 * E_UI)            { int j = i - E_UI; gdst = B1 + ui_col[j]; src = ui_row[j]; }
    else if (i < 2 * E_UI + E_UB)     { int j = i - 2 * E_UI; gdst = B2 + ub_row[j]; src = ub_col[j]; }
    else if (i < 2 * E_UI + 2 * E_UB) { int j = i - 2 * E_UI - E_UB; gdst = B3 + ub_col[j]; src = ub_row[j]; }
    else                              { int j = i - 2 * E_UI - 2 * E_UB; gdst = B4 + bi_row[j]; src = bi_col[j]; }
}

// Phase A: tile-local counting sort by coarse bucket; bbuf entry: (src<<12)|(gdst&4095)
// Edges decoded ONCE, cached in registers across the two passes (EPT=16 -> 32 VGPRs).
__global__ __launch_bounds__(256) void binA_k(
        const int* __restrict__ ui_row, const int* __restrict__ ui_col,
        const int* __restrict__ ub_row, const int* __restrict__ ub_col,
        const int* __restrict__ bi_row, const int* __restrict__ bi_col,
        int E_UI, int E_UB, int E_BI, int ETOT,
        int* __restrict__ gcur, int* __restrict__ bbuf) {
    __shared__ int hist[NBKT], runStart[NBKT], gbase[NBKT], cnt2[NBKT];
    __shared__ int ord[TILE];
    __shared__ int gpos[TILE];
    int tid = threadIdx.x;
    for (int b = tid; b < NBKT; b += 256) { hist[b] = 0; cnt2[b] = 0; }
    __syncthreads();
    int base = blockIdx.x * TILE;
    int gd[EPT], sr[EPT];
#pragma unroll
    for (int k = 0; k < EPT; k++) {
        int i = base + k * 256 + tid;
        gd[k] = -1;
        if (i < ETOT) {
            decode_edge(i, ui_row, ui_col, ub_row, ub_col, bi_row, bi_col,
                        E_UI, E_UB, E_BI, gd[k], sr[k]);
            atomicAdd(&hist[gd[k] >> BKT_SHIFT], 1);
        }
    }
    __syncthreads();
    if (tid == 0) {
        int run = 0;
        for (int b = 0; b < NBKT; b++) { runStart[b] = run; run += hist[b]; }
    }
    __syncthreads();
    if (tid < NBKT && hist[tid] > 0) gbase[tid] = atomicAdd(&gcur[tid], hist[tid]);
    __syncthreads();
#pragma unroll
    for (int k = 0; k < EPT; k++) {
        if (gd[k] >= 0) {
            int b = gd[k] >> BKT_SHIFT;
            int loc = runStart[b] + atomicAdd(&cnt2[b], 1);
            ord[loc] = (sr[k] << BKT_SHIFT) | (gd[k] & (ROWS_PER_BKT - 1));
            gpos[loc] = gbase[b] + (loc - runStart[b]);
        }
    }
    __syncthreads();
    int tcnt = runStart[NBKT - 1] + hist[NBKT - 1];
    for (int i = tid; i < tcnt; i += 256) bbuf[gpos[i]] = ord[i];
}

// Phase B: per-bucket row degree histogram + local scan -> writes rowptr AND
// places edges. Eliminates the global 500K-bin histogram + 3 scan kernels.
__global__ __launch_bounds__(1024) void binB_k(const int* __restrict__ gbase,
                                               const int* __restrict__ bbuf,
                                               int* __restrict__ rowptr,
                                               int* __restrict__ ebuf) {
    __shared__ int lh[ROWS_PER_BKT];   // histogram -> cursors
    __shared__ int ws[16];
    int bkt = blockIdx.x;
    int tid = threadIdx.x;
    int s = gbase[bkt], e = gbase[bkt + 1];
    int rbase = bkt << BKT_SHIFT;
    int nrows = RTOT - rbase;
    if (nrows > ROWS_PER_BKT) nrows = ROWS_PER_BKT;
    for (int r = tid; r < ROWS_PER_BKT; r += 1024) lh[r] = 0;
    __syncthreads();
    // pass 1: local degree histogram
    for (int i = s + tid; i < e; i += 1024)
        atomicAdd(&lh[bbuf[i] & (ROWS_PER_BKT - 1)], 1);
    __syncthreads();
    // block exclusive scan of 4096 entries (4 per thread)
    int base = tid * 4;
    int v0 = lh[base], v1 = lh[base + 1], v2 = lh[base + 2], v3 = lh[base + 3];
    int tsum = v0 + v1 + v2 + v3;
    int lane = tid & 63, w = tid >> 6;
    int x = tsum;
#pragma unroll
    for (int off = 1; off < 64; off <<= 1) {
        int y = __shfl_up(x, off, 64);
        if (lane >= off) x += y;
    }
    if (lane == 63) ws[w] = x;
    __syncthreads();
    if (tid == 0) {
        int run = 0;
#pragma unroll
        for (int k = 0; k < 16; k++) { int t = ws[k]; ws[k] = run; run += t; }
    }
    __syncthreads();
    int p0 = s + ws[w] + (x - tsum);
    int p1 = p0 + v0, p2 = p1 + v1, p3 = p2 + v2;
    lh[base] = p0; lh[base + 1] = p1; lh[base + 2] = p2; lh[base + 3] = p3;
    if (base + 3 < nrows) {
        int4 rp = {p0, p1, p2, p3};
        *reinterpret_cast<int4*>(rowptr + rbase + base) = rp;
    } else {
        if (base < nrows)     rowptr[rbase + base] = p0;
        if (base + 1 < nrows) rowptr[rbase + base + 1] = p1;
        if (base + 2 < nrows) rowptr[rbase + base + 2] = p2;
        if (base + 3 < nrows) rowptr[rbase + base + 3] = p3;
    }
    __syncthreads();
    // pass 2: place edges
    for (int i = s + tid; i < e; i += 1024) {
        int entry = bbuf[i];
        int r = entry & (ROWS_PER_BKT - 1);
        int pos = atomicAdd(&lh[r], 1);
        ebuf[pos] = (entry >> BKT_SHIFT) << 7;
    }
}

// ======================= pull machinery (bf16, 8 lanes/row) =======================
// wave = 8 rows; lane l: group = l>>3 (row), q = (l&7)*16B (8 dims as bf16x8).
// Rows are visited in degree-sorted (perm) order so all 8 groups of a wave have
// (nearly) identical trip counts.

__device__ __forceinline__ void pull8(int s, int e, const int* __restrict__ ebuf,
                                      const char* __restrict__ baseq, float* a) {
    int j = s;
    for (; j + 3 < e; j += 4) {
        int c0 = ebuf[j], c1 = ebuf[j + 1], c2 = ebuf[j + 2], c3 = ebuf[j + 3];
        uint4 v0 = *reinterpret_cast<const uint4*>(baseq + c0);
        uint4 v1 = *reinterpret_cast<const uint4*>(baseq + c1);
        uint4 v2 = *reinterpret_cast<const uint4*>(baseq + c2);
        uint4 v3 = *reinterpret_cast<const uint4*>(baseq + c3);
        addbf8(v0, a); addbf8(v1, a); addbf8(v2, a); addbf8(v3, a);
    }
    for (; j < e; ++j) {
        uint4 v = *reinterpret_cast<const uint4*>(baseq + ebuf[j]);
        addbf8(v, a);
    }
}

__device__ __forceinline__ float rowsum8(float s) {
    s += __shfl_xor(s, 1, 64);
    s += __shfl_xor(s, 2, 64);
    s += __shfl_xor(s, 4, 64);
    return s;
}

// stage1: all four layer-1 pulls fused; bf16 in, bf16 out, no cross-lane needed
__global__ void stage1_k(const int* __restrict__ rowptr, const int* __restrict__ ebuf,
                         const int* __restrict__ perm,
                         const ushort_t* __restrict__ Ubh, const ushort_t* __restrict__ Ibh,
                         const ushort_t* __restrict__ Bbh,
                         ushort_t* __restrict__ f1u_ui, ushort_t* __restrict__ f1i_ui,
                         ushort_t* __restrict__ f1u_ub, ushort_t* __restrict__ f1b_ub) {
    int gr0 = blockIdx.x * 32 + (threadIdx.x >> 3);
    if (gr0 >= B4) return;
    int gr = perm[gr0];
    int q = (threadIdx.x & 7) << 4;
    const ushort_t* src; ushort_t* dst; int row;
    if (gr < B1)      { src = Ibh; dst = f1u_ui; row = gr; }
    else if (gr < B2) { src = Ubh; dst = f1i_ui; row = gr - B1; }
    else if (gr < B3) { src = Bbh; dst = f1u_ub; row = gr - B2; }
    else              { src = Ubh; dst = f1b_ub; row = gr - B3; }
    int s = rowptr[gr], e = rowptr[gr + 1];
    float a[8] = {0, 0, 0, 0, 0, 0, 0, 0};
    pull8(s, e, ebuf, (const char*)src + q, a);
    *reinterpret_cast<uint4*>((char*)dst + (size_t)row * 128 + q) = pack8(a);
}

// finalize: out(f32) = base + l2norm(self) + l2norm(acc)
__device__ __forceinline__ void fin8_f32(const float* a, const ushort_t* selfbh,
                                         const float* basef, float* out, int row, int l) {
    int q = l << 4;
    uint4 sv = *reinterpret_cast<const uint4*>((const char*)selfbh + (size_t)row * 128 + q);
    float v[8] = {0, 0, 0, 0, 0, 0, 0, 0};
    addbf8(sv, v);
    float s1 = 0.f, s2 = 0.f;
#pragma unroll
    for (int k = 0; k < 8; k++) { s1 = fmaf(v[k], v[k], s1); s2 = fmaf(a[k], a[k], s2); }
    s1 = rowsum8(s1);
    s2 = rowsum8(s2);
    float i1 = 1.0f / fmaxf(sqrtf(s1), 1e-12f);
    float i2 = 1.0f / fmaxf(sqrtf(s2), 1e-12f);
    const float4 b0 = *reinterpret_cast<const float4*>(basef + (size_t)row * D + l * 8);
    const float4 b1 = *reinterpret_cast<const float4*>(basef + (size_t)row * D + l * 8 + 4);
    float4 o0, o1;
    o0.x = b0.x + v[0] * i1 + a[0] * i2;
    o0.y = b0.y + v[1] * i1 + a[1] * i2;
    o0.z = b0.z + v[2] * i1 + a[2] * i2;
    o0.w = b0.w + v[3] * i1 + a[3] * i2;
    o1.x = b1.x + v[4] * i1 + a[4] * i2;
    o1.y = b1.y + v[5] * i1 + a[5] * i2;
    o1.z = b1.z + v[6] * i1 + a[6] * i2;
    o1.w = b1.w + v[7] * i1 + a[7] * i2;
    *reinterpret_cast<float4*>(out + (size_t)row * 128 + l * 8) = o0;
    *reinterpret_cast<float4*>(out + (size_t)row * 128 + l * 8 + 4) = o1;
}

// stage2a: ui-user, ub-user, ub-bundle finalize fused -> f32 outputs
__global__ void stage2a_k(const int* __restrict__ rowptr, const int* __restrict__ ebuf,
                          const int* __restrict__ perm,
                          const float* __restrict__ U, const float* __restrict__ Bf,
                          const ushort_t* __restrict__ f1u_ui, const ushort_t* __restrict__ f1i_ui,
                          const ushort_t* __restrict__ f1u_ub, const ushort_t* __restrict__ f1b_ub,
                          float* __restrict__ outU, float* __restrict__ outB) {
    int t = blockIdx.x * 32 + (threadIdx.x >> 3);
    if (t >= 2 * NU + NB) return;
    int l = threadIdx.x & 7;
    int cr, row; const ushort_t* src; const ushort_t* self; const float* basef; float* out;
    if (t < NU)          { cr = perm[t];               src = f1i_ui; self = f1u_ui; basef = U;  out = outU;      row = cr; }
    else if (t < 2 * NU) { cr = perm[B2 + t - NU];     src = f1b_ub; self = f1u_ub; basef = U;  out = outU + 64; row = cr - B2; }
    else                 { cr = perm[B3 + t - 2 * NU]; src = f1u_ub; self = f1b_ub; basef = Bf; out = outB + 64; row = cr - B3; }
    int q = l << 4;
    int s = rowptr[cr], e = rowptr[cr + 1];
    float a[8] = {0, 0, 0, 0, 0, 0, 0, 0};
    pull8(s, e, ebuf, (const char*)src + q, a);
    fin8_f32(a, self, basef, out, row, l);
}

// stage2b: ui-item finalize; acc_i written IN PLACE (bf16) over f1i_ui
__global__ void stage2b_k(const int* __restrict__ rowptr, const int* __restrict__ ebuf,
                          const int* __restrict__ perm,
                          const float* __restrict__ I, const ushort_t* __restrict__ f1u_ui,
                          ushort_t* __restrict__ f1i_ui) {
    int t = blockIdx.x * 32 + (threadIdx.x >> 3);
    if (t >= NI) return;
    int l = threadIdx.x & 7;
    int q = l << 4;
    int cr = perm[B1 + t];
    int row = cr - B1;
    int s = rowptr[cr], e = rowptr[cr + 1];
    float a[8] = {0, 0, 0, 0, 0, 0, 0, 0};
    pull8(s, e, ebuf, (const char*)f1u_ui + q, a);
    uint4 sv = *reinterpret_cast<const uint4*>((const char*)f1i_ui + (size_t)row * 128 + q);
    float v[8] = {0, 0, 0, 0, 0, 0, 0, 0};
    addbf8(sv, v);
    float s1 = 0.f, s2 = 0.f;
#pragma unroll
    for (int k = 0; k < 8; k++) { s1 = fmaf(v[k], v[k], s1); s2 = fmaf(a[k], a[k], s2); }
    s1 = rowsum8(s1);
    s2 = rowsum8(s2);
    float i1 = 1.0f / fmaxf(sqrtf(s1), 1e-12f);
    float i2 = 1.0f / fmaxf(sqrtf(s2), 1e-12f);
    const float4 b0 = *reinterpret_cast<const float4*>(I + (size_t)row * D + l * 8);
    const float4 b1 = *reinterpret_cast<const float4*>(I + (size_t)row * D + l * 8 + 4);
    float o[8];
    o[0] = b0.x + v[0] * i1 + a[0] * i2;
    o[1] = b0.y + v[1] * i1 + a[1] * i2;
    o[2] = b0.z + v[2] * i1 + a[2] * i2;
    o[3] = b0.w + v[3] * i1 + a[3] * i2;
    o[4] = b1.x + v[4] * i1 + a[4] * i2;
    o[5] = b1.y + v[5] * i1 + a[5] * i2;
    o[6] = b1.z + v[6] * i1 + a[6] * i2;
    o[7] = b1.w + v[7] * i1 + a[7] * i2;
    *reinterpret_cast<uint4*>((char*)f1i_ui + (size_t)row * 128 + q) = pack8(o);
}

// stage3: weighted bi aggregation from bf16 acc_i -> outB[:,0:64] (f32)
__global__ void stage3_k(const int* __restrict__ rowptr, const int* __restrict__ ebuf,
                         const int* __restrict__ perm,
                         const ushort_t* __restrict__ acc_i, float* __restrict__ outB) {
    int t = blockIdx.x * 32 + (threadIdx.x >> 3);
    if (t >= NB) return;
    int l = threadIdx.x & 7;
    int q = l << 4;
    int cr = perm[B4 + t];
    int row = cr - B4;
    int s = rowptr[cr], e = rowptr[cr + 1];
    float a[8] = {0, 0, 0, 0, 0, 0, 0, 0};
    pull8(s, e, ebuf, (const char*)acc_i + q, a);
    float w = 1.0f / ((float)(e - s) + 1e-8f);
    float4 o0 = {a[0] * w, a[1] * w, a[2] * w, a[3] * w};
    float4 o1 = {a[4] * w, a[5] * w, a[6] * w, a[7] * w};
    *reinterpret_cast<float4*>(outB + (size_t)row * 128 + l * 8) = o0;
    *reinterpret_cast<float4*>(outB + (size_t)row * 128 + l * 8 + 4) = o1;
}

extern "C" void kernel_launch(void* const* d_in, const int* in_sizes, int n_in,
                              void* d_out, int out_size, void* d_ws, size_t ws_size,
                              hipStream_t stream) {
    const float* U = (const float*)d_in[0];
    const float* I = (const float*)d_in[1];
    const float* B = (const float*)d_in[2];
    const int* ui_row = (const int*)d_in[3];
    const int* ui_col = (const int*)d_in[4];
    const int* ub_row = (const int*)d_in[5];
    const int* ub_col = (const int*)d_in[6];
    const int* bi_row = (const int*)d_in[7];
    const int* bi_col = (const int*)d_in[8];
    const int E_UI = in_sizes[3], E_UB = in_sizes[5], E_BI = in_sizes[7];
    const int ETOT = 2 * E_UI + 2 * E_UB + E_BI;

    // workspace layout (~146 MB): bf16 tables + bf16 intermediates + CSR + perm
    ushort_t* Ubh    = (ushort_t*)d_ws;                 // NU*D
    ushort_t* Ibh    = Ubh + (size_t)NU * D;            // NI*D
    ushort_t* Bbh    = Ibh + (size_t)NI * D;            // NB*D
    ushort_t* f1u_ui = Bbh + (size_t)NB * D;            // NU*D
    ushort_t* f1i_ui = f1u_ui + (size_t)NU * D;         // NI*D (becomes acc_i)
    ushort_t* f1u_ub = f1i_ui + (size_t)NI * D;         // NU*D
    ushort_t* f1b_ub = f1u_ub + (size_t)NU * D;         // NB*D
    int* rowptr    = (int*)(f1b_ub + (size_t)NB * D);   // RTOT+1
    int* gcur      = rowptr + (RTOT + 1);               // 128
    int* gbase     = gcur + 128;                        // 128 (uses NBKT+1)
    int* gbins     = gbase + 128;                       // PTOT (320)
    int* ebuf      = gbins + PTOT;                      // ETOT
    int* bbuf      = ebuf + ETOT;                       // ETOT
    int* perm      = bbuf + ETOT;                       // RTOT

    float* outU = (float*)d_out;            // NU x 128 (IL_u | BL_u)
    float* outB = outU + (size_t)NU * 128;  // NB x 128 (IL_b | BL_b)

    const int T = 256;
    const int NCVT = (NU + NI + NB) * D / 8;

    // ---- bf16 table conversion ----
    cvt_all_k<<<(NCVT + T - 1) / T, T, 0, stream>>>(U, I, B, Ubh, Ibh, Bbh);

    // ---- bucket-level CSR build (no 500K-bin global histogram) ----
    hipMemsetAsync(gbase, 0, (128 + PTOT) * sizeof(int), stream);  // gbase + gbins
    bhist_k<<<1280, T, 0, stream>>>(ui_row, ui_col, ub_row, ub_col, bi_row,
                                    E_UI, E_UB, E_BI, ETOT, gbase);
    bscan_k<<<1, 64, 0, stream>>>(gbase, gcur, rowptr);

    // ---- edge binning (binB also derives per-row rowptr locally) ----
    binA_k<<<(ETOT + TILE - 1) / TILE, 256, 0, stream>>>(ui_row, ui_col, ub_row, ub_col,
                                                         bi_row, bi_col, E_UI, E_UB, E_BI,
                                                         ETOT, gcur, bbuf);
    binB_k<<<NBKT, 1024, 0, stream>>>(gbase, bbuf, rowptr, ebuf);

    // ---- degree-uniform row permutation (removes pull-loop divergence) ----
    permhist_k<<<(RTOT + 255) / 256, 256, 0, stream>>>(rowptr, gbins);
    permscan_k<<<1, 64, 0, stream>>>(gbins);
    permscat_k<<<(RTOT + 2047) / 2048, 256, 0, stream>>>(rowptr, gbins, perm);

    // ---- stage1: all four layer-1 pulls ----
    stage1_k<<<(B4 + 31) / 32, T, 0, stream>>>(rowptr, ebuf, perm, Ubh, Ibh, Bbh,
                                               f1u_ui, f1i_ui, f1u_ub, f1b_ub);
    // ---- stage2a: ui-user, ub-user, ub-bundle finalize ----
    stage2a_k<<<(2 * NU + NB + 31) / 32, T, 0, stream>>>(rowptr, ebuf, perm, U, B,
                                                         f1u_ui, f1i_ui, f1u_ub, f1b_ub,
                                                         outU, outB);
    // ---- stage2b: ui-item finalize (in-place bf16 acc_i) ----
    stage2b_k<<<(NI + 31) / 32, T, 0, stream>>>(rowptr, ebuf, perm, I, f1u_ui, f1i_ui);
    // ---- stage3: weighted bi aggregation ----
    stage3_k<<<(NB + 31) / 32, T, 0, stream>>>(rowptr, ebuf, perm, f1i_ui, outB);
}

// Round 9
// 482.208 us; speedup vs baseline: 1.3764x; 1.1036x over previous
//
#include <hip/hip_runtime.h>
#include <hip/hip_bf16.h>

// Problem constants (match reference setup_inputs)
#define NU 100000
#define NI 200000
#define NB 50000
#define D  64

// Concatenated CSR row-space: 5 graph directions
#define B0 0
#define B1 (NU)
#define B2 (NU + NI)
#define B3 (2 * NU + NI)
#define B4 (2 * NU + NI + NB)
#define RTOT (2 * NU + NI + 2 * NB)   // 500000 rows total

// Bucketing for the two-phase edge sort
// BKT_SHIFT=10: 489 buckets -> binB grid covers all 256 CUs (was 123 blocks,
// 7.5% occupancy, latency-bound at 93us).
#define BKT_SHIFT 10
#define ROWS_PER_BKT 1024
#define NBKT ((RTOT + ROWS_PER_BKT - 1) / ROWS_PER_BKT)   // 489
#define NBKT_PAD 512
#define TILE 4096
#define EPT (TILE / 256)

// Degree-permutation bins: 5 segments x 64 degree bins
#define PBINS 64
#define PTOT (5 * PBINS)

typedef unsigned short ushort_t;

// ======================= bf16 helpers =======================

__device__ __forceinline__ unsigned f2bf(float f) {
    unsigned u = __float_as_uint(f);
    return (u + 0x7FFFu + ((u >> 16) & 1u)) >> 16;   // RNE
}

__device__ __forceinline__ uint4 pack8(const float* a) {
    uint4 o;
    o.x = f2bf(a[0]) | (f2bf(a[1]) << 16);
    o.y = f2bf(a[2]) | (f2bf(a[3]) << 16);
    o.z = f2bf(a[4]) | (f2bf(a[5]) << 16);
    o.w = f2bf(a[6]) | (f2bf(a[7]) << 16);
    return o;
}

__device__ __forceinline__ void addbf8(uint4 v, float* a) {
    a[0] += __uint_as_float(v.x << 16);
    a[1] += __uint_as_float(v.x & 0xFFFF0000u);
    a[2] += __uint_as_float(v.y << 16);
    a[3] += __uint_as_float(v.y & 0xFFFF0000u);
    a[4] += __uint_as_float(v.z << 16);
    a[5] += __uint_as_float(v.z & 0xFFFF0000u);
    a[6] += __uint_as_float(v.w << 16);
    a[7] += __uint_as_float(v.w & 0xFFFF0000u);
}

// f32 tables -> bf16 tables (one fused launch; 8 elems/thread)
__global__ void cvt_all_k(const float* __restrict__ U, const float* __restrict__ I,
                          const float* __restrict__ Bf,
                          ushort_t* __restrict__ Ubh, ushort_t* __restrict__ Ibh,
                          ushort_t* __restrict__ Bbh) {
    int t = blockIdx.x * blockDim.x + threadIdx.x;
    const int nU = NU * D / 8, nI = NI * D / 8, nB = NB * D / 8;
    const float* s; ushort_t* d;
    if (t < nU)           { s = U;  d = Ubh; }
    else if (t < nU + nI) { s = I;  d = Ibh; t -= nU; }
    else if (t < nU + nI + nB) { s = Bf; d = Bbh; t -= nU + nI; }
    else return;
    const float4 f0 = *reinterpret_cast<const float4*>(s + (size_t)t * 8);
    const float4 f1 = *reinterpret_cast<const float4*>(s + (size_t)t * 8 + 4);
    float a[8] = {f0.x, f0.y, f0.z, f0.w, f1.x, f1.y, f1.z, f1.w};
    *reinterpret_cast<uint4*>(d + (size_t)t * 8) = pack8(a);
}

// ======================= bucket histogram =======================
// 489 coarse buckets; LDS-staged so global atomics drop to NBKT per block.

__global__ __launch_bounds__(256) void bhist_k(
        const int* __restrict__ ui_row, const int* __restrict__ ui_col,
        const int* __restrict__ ub_row, const int* __restrict__ ub_col,
        const int* __restrict__ bi_row,
        int E_UI, int E_UB, int E_BI, int ETOT, int* __restrict__ gbase) {
    __shared__ int h[NBKT];
    int tid = threadIdx.x;
    for (int b = tid; b < NBKT; b += 256) h[b] = 0;
    __syncthreads();
    for (int i = blockIdx.x * 256 + tid; i < ETOT; i += gridDim.x * 256) {
        int gdst;
        if (i < E_UI)                     gdst = B0 + ui_row[i];
        else if (i < 2 * E_UI)            gdst = B1 + ui_col[i - E_UI];
        else if (i < 2 * E_UI + E_UB)     gdst = B2 + ub_row[i - 2 * E_UI];
        else if (i < 2 * E_UI + 2 * E_UB) gdst = B3 + ub_col[i - 2 * E_UI - E_UB];
        else                              gdst = B4 + bi_row[i - 2 * E_UI - 2 * E_UB];
        atomicAdd(&h[gdst >> BKT_SHIFT], 1);
    }
    __syncthreads();
    for (int b = tid; b < NBKT; b += 256)
        if (h[b]) atomicAdd(&gbase[b], h[b]);
}

// one-wave exclusive scan of the 489 bucket counts -> gbase (bases), gcur copy.
// 8 entries per lane. Also sets gbase[NBKT] = ETOT and rowptr[RTOT] = ETOT.
__global__ void bscan_k(int* __restrict__ gbase, int* __restrict__ gcur,
                        int* __restrict__ rowptr) {
    int lane = threadIdx.x;  // 64
    int vals[8];
    int s = 0;
#pragma unroll
    for (int k = 0; k < 8; k++) {
        int id = lane * 8 + k;
        vals[k] = (id < NBKT) ? gbase[id] : 0;
        s += vals[k];
    }
    int x = s;
#pragma unroll
    for (int off = 1; off < 64; off <<= 1) {
        int y = __shfl_up(x, off, 64);
        if (lane >= off) x += y;
    }
    int excl = x - s;
#pragma unroll
    for (int k = 0; k < 8; k++) {
        int id = lane * 8 + k;
        if (id <= NBKT) { gbase[id] = excl; if (id < NBKT) gcur[id] = excl; }
        excl += vals[k];
    }
    if (lane == 63) rowptr[RTOT] = x;   // total == ETOT
}

// ======================= degree-uniform row permutation =======================
// Counting sort of rows by (segment, min(degree,63)) so each 8-row wave-group in
// the pull stages has uniform trip count (kills exec-mask divergence in pull8).

__device__ __forceinline__ int seg_of_row(int r) {
    return (r < B1) ? 0 : (r < B2) ? 1 : (r < B3) ? 2 : (r < B4) ? 3 : 4;
}

// pass 1: global histogram of (seg, degbin)
__global__ void permhist_k(const int* __restrict__ rowptr, int* __restrict__ gbins) {
    __shared__ int h[PTOT];
    int tid = threadIdx.x;
    for (int i = tid; i < PTOT; i += 256) h[i] = 0;
    __syncthreads();
    int r = blockIdx.x * 256 + tid;
    if (r < RTOT) {
        int d = rowptr[r + 1] - rowptr[r];
        int bin = d < PBINS ? d : PBINS - 1;
        atomicAdd(&h[seg_of_row(r) * PBINS + bin], 1);
    }
    __syncthreads();
    for (int i = tid; i < PTOT; i += 256)
        if (h[i]) atomicAdd(&gbins[i], h[i]);
}

// pass 2: exclusive scan of the 320 bins (seg-major order => segments stay
// contiguous at their natural bases). 64 threads x 5 values.
__global__ void permscan_k(int* __restrict__ gbins) {
    int lane = threadIdx.x;  // 64
    int vals[5];
    int s = 0;
#pragma unroll
    for (int k = 0; k < 5; k++) { vals[k] = gbins[lane * 5 + k]; s += vals[k]; }
    int x = s;
#pragma unroll
    for (int off = 1; off < 64; off <<= 1) {
        int y = __shfl_up(x, off, 64);
        if (lane >= off) x += y;
    }
    int excl = x - s;
#pragma unroll
    for (int k = 0; k < 5; k++) { gbins[lane * 5 + k] = excl; excl += vals[k]; }
}

// pass 3: two-phase scatter (block-local count -> reserve global base -> place)
__global__ __launch_bounds__(256) void permscat_k(const int* __restrict__ rowptr,
                                                  int* __restrict__ gbins,
                                                  int* __restrict__ perm) {
    __shared__ int h[PTOT], bs[PTOT], c2[PTOT];
    int tid = threadIdx.x;
    for (int i = tid; i < PTOT; i += 256) { h[i] = 0; c2[i] = 0; }
    __syncthreads();
    int r0 = blockIdx.x * 2048;
    int sb[8];
#pragma unroll
    for (int k = 0; k < 8; k++) {
        int r = r0 + k * 256 + tid;
        if (r < RTOT) {
            int d = rowptr[r + 1] - rowptr[r];
            int bin = d < PBINS ? d : PBINS - 1;
            sb[k] = seg_of_row(r) * PBINS + bin;
            atomicAdd(&h[sb[k]], 1);
        } else sb[k] = -1;
    }
    __syncthreads();
    for (int i = tid; i < PTOT; i += 256)
        if (h[i]) bs[i] = atomicAdd(&gbins[i], h[i]);
    __syncthreads();
#pragma unroll
    for (int k = 0; k < 8; k++) {
        if (sb[k] >= 0) {
            int r = r0 + k * 256 + tid;
            int loc = atomicAdd(&c2[sb[k]], 1);
            perm[bs[sb[k]] + loc] = r;
        }
    }
}

// ======================= edge binning =======================

__device__ __forceinline__ void decode_edge(int i,
        const int* __restrict__ ui_row, const int* __restrict__ ui_col,
        const int* __restrict__ ub_row, const int* __restrict__ ub_col,
        const int* __restrict__ bi_row, const int* __restrict__ bi_col,
        int E_UI, int E_UB, int E_BI, int& gdst, int& src) {
    if (i < E_UI)                     { gdst = B0 + ui_row[i]; src = ui_col[i]; }
    else if (i < 2 * E_UI)            { int j = i - E_UI; gdst = B1 + ui_col[j]; src = ui_row[j]; }
    else if (i < 2 * E_UI + E_UB)     { int j = i - 2 * E_UI; gdst = B2 + ub_row[j]; src = ub_col[j]; }
    else if (i < 2 * E_UI + 2 * E_UB) { int j = i - 2 * E_UI - E_UB; gdst = B3 + ub_col[j]; src = ub_row[j]; }
    else                              { int j = i - 2 * E_UI - 2 * E_UB; gdst = B4 + bi_row[j]; src = bi_col[j]; }
}

// Phase A: tile-local counting sort by coarse bucket; bbuf entry: (src<<10)|(gdst&1023)
// Edges decoded ONCE, cached in registers across the two passes (EPT=16 -> 32 VGPRs).
__global__ __launch_bounds__(256) void binA_k(
        const int* __restrict__ ui_row, const int* __restrict__ ui_col,
        const int* __restrict__ ub_row, const int* __restrict__ ub_col,
        const int* __restrict__ bi_row, const int* __restrict__ bi_col,
        int E_UI, int E_UB, int E_BI, int ETOT,
        int* __restrict__ gcur, int* __restrict__ bbuf) {
    __shared__ int hist[NBKT], runStart[NBKT], gbase[NBKT], cnt2[NBKT];
    __shared__ int ord[TILE];
    __shared__ int gpos[TILE];
    int tid = threadIdx.x;
    for (int b = tid; b < NBKT; b += 256) { hist[b] = 0; cnt2[b] = 0; }
    __syncthreads();
    int base = blockIdx.x * TILE;
    int gd[EPT], sr[EPT];
#pragma unroll
    for (int k = 0; k < EPT; k++) {
        int i = base + k * 256 + tid;
        gd[k] = -1;
        if (i < ETOT) {
            decode_edge(i, ui_row, ui_col, ub_row, ub_col, bi_row, bi_col,
                        E_UI, E_UB, E_BI, gd[k], sr[k]);
            atomicAdd(&hist[gd[k] >> BKT_SHIFT], 1);
        }
    }
    __syncthreads();
    if (tid == 0) {
        int run = 0;
        for (int b = 0; b < NBKT; b++) { runStart[b] = run; run += hist[b]; }
    }
    __syncthreads();
    for (int b = tid; b < NBKT; b += 256)
        if (hist[b] > 0) gbase[b] = atomicAdd(&gcur[b], hist[b]);
    __syncthreads();
#pragma unroll
    for (int k = 0; k < EPT; k++) {
        if (gd[k] >= 0) {
            int b = gd[k] >> BKT_SHIFT;
            int loc = runStart[b] + atomicAdd(&cnt2[b], 1);
            ord[loc] = (sr[k] << BKT_SHIFT) | (gd[k] & (ROWS_PER_BKT - 1));
            gpos[loc] = gbase[b] + (loc - runStart[b]);
        }
    }
    __syncthreads();
    int tcnt = runStart[NBKT - 1] + hist[NBKT - 1];
    for (int i = tid; i < tcnt; i += 256) bbuf[gpos[i]] = ord[i];
}

// Phase B: per-bucket row degree histogram + local scan -> writes rowptr AND
// places edges. 489 blocks x 1024 threads: all CUs busy (was 123 blocks / 7.5% occ).
__global__ __launch_bounds__(1024) void binB_k(const int* __restrict__ gbase,
                                               const int* __restrict__ bbuf,
                                               int* __restrict__ rowptr,
                                               int* __restrict__ ebuf) {
    __shared__ int lh[ROWS_PER_BKT];   // histogram -> exclusive offsets -> cursors
    __shared__ int ws[16];
    int bkt = blockIdx.x;
    int tid = threadIdx.x;
    int s = gbase[bkt], e = gbase[bkt + 1];
    int rbase = bkt << BKT_SHIFT;
    int nrows = RTOT - rbase;
    if (nrows > ROWS_PER_BKT) nrows = ROWS_PER_BKT;
    lh[tid] = 0;
    __syncthreads();
    // pass 1: local degree histogram
    for (int i = s + tid; i < e; i += 1024)
        atomicAdd(&lh[bbuf[i] & (ROWS_PER_BKT - 1)], 1);
    __syncthreads();
    // block exclusive scan of 1024 entries (1 per thread)
    int v = lh[tid];
    int lane = tid & 63, w = tid >> 6;
    int x = v;
#pragma unroll
    for (int off = 1; off < 64; off <<= 1) {
        int y = __shfl_up(x, off, 64);
        if (lane >= off) x += y;
    }
    if (lane == 63) ws[w] = x;
    __syncthreads();
    if (tid == 0) {
        int run = 0;
#pragma unroll
        for (int k = 0; k < 16; k++) { int t = ws[k]; ws[k] = run; run += t; }
    }
    __syncthreads();
    int p = s + ws[w] + (x - v);   // exclusive offset for row tid
    lh[tid] = p;
    if (tid < nrows) rowptr[rbase + tid] = p;
    __syncthreads();
    // pass 2: place edges
    for (int i = s + tid; i < e; i += 1024) {
        int entry = bbuf[i];
        int r = entry & (ROWS_PER_BKT - 1);
        int pos = atomicAdd(&lh[r], 1);
        ebuf[pos] = (entry >> BKT_SHIFT) << 7;
    }
}

// ======================= pull machinery (bf16, 8 lanes/row) =======================
// wave = 8 rows; lane l: group = l>>3 (row), q = (l&7)*16B (8 dims as bf16x8).
// Rows are visited in degree-sorted (perm) order so all 8 groups of a wave have
// (nearly) identical trip counts.

__device__ __forceinline__ void pull8(int s, int e, const int* __restrict__ ebuf,
                                      const char* __restrict__ baseq, float* a) {
    int j = s;
    for (; j + 3 < e; j += 4) {
        int c0 = ebuf[j], c1 = ebuf[j + 1], c2 = ebuf[j + 2], c3 = ebuf[j + 3];
        uint4 v0 = *reinterpret_cast<const uint4*>(baseq + c0);
        uint4 v1 = *reinterpret_cast<const uint4*>(baseq + c1);
        uint4 v2 = *reinterpret_cast<const uint4*>(baseq + c2);
        uint4 v3 = *reinterpret_cast<const uint4*>(baseq + c3);
        addbf8(v0, a); addbf8(v1, a); addbf8(v2, a); addbf8(v3, a);
    }
    for (; j < e; ++j) {
        uint4 v = *reinterpret_cast<const uint4*>(baseq + ebuf[j]);
        addbf8(v, a);
    }
}

__device__ __forceinline__ float rowsum8(float s) {
    s += __shfl_xor(s, 1, 64);
    s += __shfl_xor(s, 2, 64);
    s += __shfl_xor(s, 4, 64);
    return s;
}

// stage1: all four layer-1 pulls fused; bf16 in, bf16 out, no cross-lane needed
__global__ void stage1_k(const int* __restrict__ rowptr, const int* __restrict__ ebuf,
                         const int* __restrict__ perm,
                         const ushort_t* __restrict__ Ubh, const ushort_t* __restrict__ Ibh,
                         const ushort_t* __restrict__ Bbh,
                         ushort_t* __restrict__ f1u_ui, ushort_t* __restrict__ f1i_ui,
                         ushort_t* __restrict__ f1u_ub, ushort_t* __restrict__ f1b_ub) {
    int gr0 = blockIdx.x * 32 + (threadIdx.x >> 3);
    if (gr0 >= B4) return;
    int gr = perm[gr0];
    int q = (threadIdx.x & 7) << 4;
    const ushort_t* src; ushort_t* dst; int row;
    if (gr < B1)      { src = Ibh; dst = f1u_ui; row = gr; }
    else if (gr < B2) { src = Ubh; dst = f1i_ui; row = gr - B1; }
    else if (gr < B3) { src = Bbh; dst = f1u_ub; row = gr - B2; }
    else              { src = Ubh; dst = f1b_ub; row = gr - B3; }
    int s = rowptr[gr], e = rowptr[gr + 1];
    float a[8] = {0, 0, 0, 0, 0, 0, 0, 0};
    pull8(s, e, ebuf, (const char*)src + q, a);
    *reinterpret_cast<uint4*>((char*)dst + (size_t)row * 128 + q) = pack8(a);
}

// finalize: out(f32) = base + l2norm(self) + l2norm(acc)
__device__ __forceinline__ void fin8_f32(const float* a, const ushort_t* selfbh,
                                         const float* basef, float* out, int row, int l) {
    int q = l << 4;
    uint4 sv = *reinterpret_cast<const uint4*>((const char*)selfbh + (size_t)row * 128 + q);
    float v[8] = {0, 0, 0, 0, 0, 0, 0, 0};
    addbf8(sv, v);
    float s1 = 0.f, s2 = 0.f;
#pragma unroll
    for (int k = 0; k < 8; k++) { s1 = fmaf(v[k], v[k], s1); s2 = fmaf(a[k], a[k], s2); }
    s1 = rowsum8(s1);
    s2 = rowsum8(s2);
    float i1 = 1.0f / fmaxf(sqrtf(s1), 1e-12f);
    float i2 = 1.0f / fmaxf(sqrtf(s2), 1e-12f);
    const float4 b0 = *reinterpret_cast<const float4*>(basef + (size_t)row * D + l * 8);
    const float4 b1 = *reinterpret_cast<const float4*>(basef + (size_t)row * D + l * 8 + 4);
    float4 o0, o1;
    o0.x = b0.x + v[0] * i1 + a[0] * i2;
    o0.y = b0.y + v[1] * i1 + a[1] * i2;
    o0.z = b0.z + v[2] * i1 + a[2] * i2;
    o0.w = b0.w + v[3] * i1 + a[3] * i2;
    o1.x = b1.x + v[4] * i1 + a[4] * i2;
    o1.y = b1.y + v[5] * i1 + a[5] * i2;
    o1.z = b1.z + v[6] * i1 + a[6] * i2;
    o1.w = b1.w + v[7] * i1 + a[7] * i2;
    *reinterpret_cast<float4*>(out + (size_t)row * 128 + l * 8) = o0;
    *reinterpret_cast<float4*>(out + (size_t)row * 128 + l * 8 + 4) = o1;
}

// stage2a: ui-user, ub-user, ub-bundle finalize fused -> f32 outputs
__global__ void stage2a_k(const int* __restrict__ rowptr, const int* __restrict__ ebuf,
                          const int* __restrict__ perm,
                          const float* __restrict__ U, const float* __restrict__ Bf,
                          const ushort_t* __restrict__ f1u_ui, const ushort_t* __restrict__ f1i_ui,
                          const ushort_t* __restrict__ f1u_ub, const ushort_t* __restrict__ f1b_ub,
                          float* __restrict__ outU, float* __restrict__ outB) {
    int t = blockIdx.x * 32 + (threadIdx.x >> 3);
    if (t >= 2 * NU + NB) return;
    int l = threadIdx.x & 7;
    int cr, row; const ushort_t* src; const ushort_t* self; const float* basef; float* out;
    if (t < NU)          { cr = perm[t];               src = f1i_ui; self = f1u_ui; basef = U;  out = outU;      row = cr; }
    else if (t < 2 * NU) { cr = perm[B2 + t - NU];     src = f1b_ub; self = f1u_ub; basef = U;  out = outU + 64; row = cr - B2; }
    else                 { cr = perm[B3 + t - 2 * NU]; src = f1u_ub; self = f1b_ub; basef = Bf; out = outB + 64; row = cr - B3; }
    int q = l << 4;
    int s = rowptr[cr], e = rowptr[cr + 1];
    float a[8] = {0, 0, 0, 0, 0, 0, 0, 0};
    pull8(s, e, ebuf, (const char*)src + q, a);
    fin8_f32(a, self, basef, out, row, l);
}

// stage2b: ui-item finalize; acc_i written IN PLACE (bf16) over f1i_ui
__global__ void stage2b_k(const int* __restrict__ rowptr, const int* __restrict__ ebuf,
                          const int* __restrict__ perm,
                          const float* __restrict__ I, const ushort_t* __restrict__ f1u_ui,
                          ushort_t* __restrict__ f1i_ui) {
    int t = blockIdx.x * 32 + (threadIdx.x >> 3);
    if (t >= NI) return;
    int l = threadIdx.x & 7;
    int q = l << 4;
    int cr = perm[B1 + t];
    int row = cr - B1;
    int s = rowptr[cr], e = rowptr[cr + 1];
    float a[8] = {0, 0, 0, 0, 0, 0, 0, 0};
    pull8(s, e, ebuf, (const char*)f1u_ui + q, a);
    uint4 sv = *reinterpret_cast<const uint4*>((const char*)f1i_ui + (size_t)row * 128 + q);
    float v[8] = {0, 0, 0, 0, 0, 0, 0, 0};
    addbf8(sv, v);
    float s1 = 0.f, s2 = 0.f;
#pragma unroll
    for (int k = 0; k < 8; k++) { s1 = fmaf(v[k], v[k], s1); s2 = fmaf(a[k], a[k], s2); }
    s1 = rowsum8(s1);
    s2 = rowsum8(s2);
    float i1 = 1.0f / fmaxf(sqrtf(s1), 1e-12f);
    float i2 = 1.0f / fmaxf(sqrtf(s2), 1e-12f);
    const float4 b0 = *reinterpret_cast<const float4*>(I + (size_t)row * D + l * 8);
    const float4 b1 = *reinterpret_cast<const float4*>(I + (size_t)row * D + l * 8 + 4);
    float o[8];
    o[0] = b0.x + v[0] * i1 + a[0] * i2;
    o[1] = b0.y + v[1] * i1 + a[1] * i2;
    o[2] = b0.z + v[2] * i1 + a[2] * i2;
    o[3] = b0.w + v[3] * i1 + a[3] * i2;
    o[4] = b1.x + v[4] * i1 + a[4] * i2;
    o[5] = b1.y + v[5] * i1 + a[5] * i2;
    o[6] = b1.z + v[6] * i1 + a[6] * i2;
    o[7] = b1.w + v[7] * i1 + a[7] * i2;
    *reinterpret_cast<uint4*>((char*)f1i_ui + (size_t)row * 128 + q) = pack8(o);
}

// stage3: weighted bi aggregation from bf16 acc_i -> outB[:,0:64] (f32)
__global__ void stage3_k(const int* __restrict__ rowptr, const int* __restrict__ ebuf,
                         const int* __restrict__ perm,
                         const ushort_t* __restrict__ acc_i, float* __restrict__ outB) {
    int t = blockIdx.x * 32 + (threadIdx.x >> 3);
    if (t >= NB) return;
    int l = threadIdx.x & 7;
    int q = l << 4;
    int cr = perm[B4 + t];
    int row = cr - B4;
    int s = rowptr[cr], e = rowptr[cr + 1];
    float a[8] = {0, 0, 0, 0, 0, 0, 0, 0};
    pull8(s, e, ebuf, (const char*)acc_i + q, a);
    float w = 1.0f / ((float)(e - s) + 1e-8f);
    float4 o0 = {a[0] * w, a[1] * w, a[2] * w, a[3] * w};
    float4 o1 = {a[4] * w, a[5] * w, a[6] * w, a[7] * w};
    *reinterpret_cast<float4*>(outB + (size_t)row * 128 + l * 8) = o0;
    *reinterpret_cast<float4*>(outB + (size_t)row * 128 + l * 8 + 4) = o1;
}

extern "C" void kernel_launch(void* const* d_in, const int* in_sizes, int n_in,
                              void* d_out, int out_size, void* d_ws, size_t ws_size,
                              hipStream_t stream) {
    const float* U = (const float*)d_in[0];
    const float* I = (const float*)d_in[1];
    const float* B = (const float*)d_in[2];
    const int* ui_row = (const int*)d_in[3];
    const int* ui_col = (const int*)d_in[4];
    const int* ub_row = (const int*)d_in[5];
    const int* ub_col = (const int*)d_in[6];
    const int* bi_row = (const int*)d_in[7];
    const int* bi_col = (const int*)d_in[8];
    const int E_UI = in_sizes[3], E_UB = in_sizes[5], E_BI = in_sizes[7];
    const int ETOT = 2 * E_UI + 2 * E_UB + E_BI;

    // workspace layout (~146 MB): bf16 tables + bf16 intermediates + CSR + perm
    ushort_t* Ubh    = (ushort_t*)d_ws;                 // NU*D
    ushort_t* Ibh    = Ubh + (size_t)NU * D;            // NI*D
    ushort_t* Bbh    = Ibh + (size_t)NI * D;            // NB*D
    ushort_t* f1u_ui = Bbh + (size_t)NB * D;            // NU*D
    ushort_t* f1i_ui = f1u_ui + (size_t)NU * D;         // NI*D (becomes acc_i)
    ushort_t* f1u_ub = f1i_ui + (size_t)NI * D;         // NU*D
    ushort_t* f1b_ub = f1u_ub + (size_t)NU * D;         // NB*D
    int* rowptr    = (int*)(f1b_ub + (size_t)NB * D);   // RTOT+1
    int* gcur      = rowptr + (RTOT + 1);               // NBKT_PAD (512)
    int* gbase     = gcur + NBKT_PAD;                   // NBKT_PAD (512, uses NBKT+1)
    int* gbins     = gbase + NBKT_PAD;                  // PTOT (320)
    int* ebuf      = gbins + PTOT;                      // ETOT
    int* bbuf      = ebuf + ETOT;                       // ETOT
    int* perm      = bbuf + ETOT;                       // RTOT

    float* outU = (float*)d_out;            // NU x 128 (IL_u | BL_u)
    float* outB = outU + (size_t)NU * 128;  // NB x 128 (IL_b | BL_b)

    const int T = 256;
    const int NCVT = (NU + NI + NB) * D / 8;

    // ---- bf16 table conversion ----
    cvt_all_k<<<(NCVT + T - 1) / T, T, 0, stream>>>(U, I, B, Ubh, Ibh, Bbh);

    // ---- bucket-level CSR build ----
    hipMemsetAsync(gbase, 0, (NBKT_PAD + PTOT) * sizeof(int), stream);  // gbase + gbins
    bhist_k<<<1280, T, 0, stream>>>(ui_row, ui_col, ub_row, ub_col, bi_row,
                                    E_UI, E_UB, E_BI, ETOT, gbase);
    bscan_k<<<1, 64, 0, stream>>>(gbase, gcur, rowptr);

    // ---- edge binning (binB also derives per-row rowptr locally) ----
    binA_k<<<(ETOT + TILE - 1) / TILE, 256, 0, stream>>>(ui_row, ui_col, ub_row, ub_col,
                                                         bi_row, bi_col, E_UI, E_UB, E_BI,
                                                         ETOT, gcur, bbuf);
    binB_k<<<NBKT, 1024, 0, stream>>>(gbase, bbuf, rowptr, ebuf);

    // ---- degree-uniform row permutation (removes pull-loop divergence) ----
    permhist_k<<<(RTOT + 255) / 256, 256, 0, stream>>>(rowptr, gbins);
    permscan_k<<<1, 64, 0, stream>>>(gbins);
    permscat_k<<<(RTOT + 2047) / 2048, 256, 0, stream>>>(rowptr, gbins, perm);

    // ---- stage1: all four layer-1 pulls ----
    stage1_k<<<(B4 + 31) / 32, T, 0, stream>>>(rowptr, ebuf, perm, Ubh, Ibh, Bbh,
                                               f1u_ui, f1i_ui, f1u_ub, f1b_ub);
    // ---- stage2a: ui-user, ub-user, ub-bundle finalize ----
    stage2a_k<<<(2 * NU + NB + 31) / 32, T, 0, stream>>>(rowptr, ebuf, perm, U, B,
                                                         f1u_ui, f1i_ui, f1u_ub, f1b_ub,
                                                         outU, outB);
    // ---- stage2b: ui-item finalize (in-place bf16 acc_i) ----
    stage2b_k<<<(NI + 31) / 32, T, 0, stream>>>(rowptr, ebuf, perm, I, f1u_ui, f1i_ui);
    // ---- stage3: weighted bi aggregation ----
    stage3_k<<<(NB + 31) / 32, T, 0, stream>>>(rowptr, ebuf, perm, f1i_ui, outB);
}

// Round 10
// 471.198 us; speedup vs baseline: 1.4085x; 1.0234x over previous
//
#include <hip/hip_runtime.h>
#include <hip/hip_bf16.h>

// Problem constants (match reference setup_inputs)
#define NU 100000
#define NI 200000
#define NB 50000
#define D  64

// Concatenated CSR row-space: 5 graph directions
#define B0 0
#define B1 (NU)
#define B2 (NU + NI)
#define B3 (2 * NU + NI)
#define B4 (2 * NU + NI + NB)
#define RTOT (2 * NU + NI + 2 * NB)   // 500000 rows total

// Bucketing for the two-phase edge sort
// BKT_SHIFT=10: 489 buckets -> binB grid covers all 256 CUs.
#define BKT_SHIFT 10
#define ROWS_PER_BKT 1024
#define NBKT ((RTOT + ROWS_PER_BKT - 1) / ROWS_PER_BKT)   // 489
#define NBKT_PAD 512
#define TILE 4096
#define EPT (TILE / 256)

// Degree-permutation bins: 5 segments x 64 degree bins
#define PBINS 64
#define PTOT (5 * PBINS)

typedef unsigned short ushort_t;

// ======================= bf16 helpers =======================

__device__ __forceinline__ unsigned f2bf(float f) {
    unsigned u = __float_as_uint(f);
    return (u + 0x7FFFu + ((u >> 16) & 1u)) >> 16;   // RNE
}

__device__ __forceinline__ uint4 pack8(const float* a) {
    uint4 o;
    o.x = f2bf(a[0]) | (f2bf(a[1]) << 16);
    o.y = f2bf(a[2]) | (f2bf(a[3]) << 16);
    o.z = f2bf(a[4]) | (f2bf(a[5]) << 16);
    o.w = f2bf(a[6]) | (f2bf(a[7]) << 16);
    return o;
}

__device__ __forceinline__ void addbf8(uint4 v, float* a) {
    a[0] += __uint_as_float(v.x << 16);
    a[1] += __uint_as_float(v.x & 0xFFFF0000u);
    a[2] += __uint_as_float(v.y << 16);
    a[3] += __uint_as_float(v.y & 0xFFFF0000u);
    a[4] += __uint_as_float(v.z << 16);
    a[5] += __uint_as_float(v.z & 0xFFFF0000u);
    a[6] += __uint_as_float(v.w << 16);
    a[7] += __uint_as_float(v.w & 0xFFFF0000u);
}

// f32 tables -> bf16 tables (one fused launch; 8 elems/thread)
__global__ void cvt_all_k(const float* __restrict__ U, const float* __restrict__ I,
                          const float* __restrict__ Bf,
                          ushort_t* __restrict__ Ubh, ushort_t* __restrict__ Ibh,
                          ushort_t* __restrict__ Bbh) {
    int t = blockIdx.x * blockDim.x + threadIdx.x;
    const int nU = NU * D / 8, nI = NI * D / 8, nB = NB * D / 8;
    const float* s; ushort_t* d;
    if (t < nU)           { s = U;  d = Ubh; }
    else if (t < nU + nI) { s = I;  d = Ibh; t -= nU; }
    else if (t < nU + nI + nB) { s = Bf; d = Bbh; t -= nU + nI; }
    else return;
    const float4 f0 = *reinterpret_cast<const float4*>(s + (size_t)t * 8);
    const float4 f1 = *reinterpret_cast<const float4*>(s + (size_t)t * 8 + 4);
    float a[8] = {f0.x, f0.y, f0.z, f0.w, f1.x, f1.y, f1.z, f1.w};
    *reinterpret_cast<uint4*>(d + (size_t)t * 8) = pack8(a);
}

// ======================= bucket histogram =======================

__global__ __launch_bounds__(256) void bhist_k(
        const int* __restrict__ ui_row, const int* __restrict__ ui_col,
        const int* __restrict__ ub_row, const int* __restrict__ ub_col,
        const int* __restrict__ bi_row,
        int E_UI, int E_UB, int E_BI, int ETOT, int* __restrict__ gbase) {
    __shared__ int h[NBKT];
    int tid = threadIdx.x;
    for (int b = tid; b < NBKT; b += 256) h[b] = 0;
    __syncthreads();
    for (int i = blockIdx.x * 256 + tid; i < ETOT; i += gridDim.x * 256) {
        int gdst;
        if (i < E_UI)                     gdst = B0 + ui_row[i];
        else if (i < 2 * E_UI)            gdst = B1 + ui_col[i - E_UI];
        else if (i < 2 * E_UI + E_UB)     gdst = B2 + ub_row[i - 2 * E_UI];
        else if (i < 2 * E_UI + 2 * E_UB) gdst = B3 + ub_col[i - 2 * E_UI - E_UB];
        else                              gdst = B4 + bi_row[i - 2 * E_UI - 2 * E_UB];
        atomicAdd(&h[gdst >> BKT_SHIFT], 1);
    }
    __syncthreads();
    for (int b = tid; b < NBKT; b += 256)
        if (h[b]) atomicAdd(&gbase[b], h[b]);
}

// one-wave exclusive scan of the 489 bucket counts -> gbase (bases), gcur copy.
__global__ void bscan_k(int* __restrict__ gbase, int* __restrict__ gcur,
                        int* __restrict__ rowptr) {
    int lane = threadIdx.x;  // 64
    int vals[8];
    int s = 0;
#pragma unroll
    for (int k = 0; k < 8; k++) {
        int id = lane * 8 + k;
        vals[k] = (id < NBKT) ? gbase[id] : 0;
        s += vals[k];
    }
    int x = s;
#pragma unroll
    for (int off = 1; off < 64; off <<= 1) {
        int y = __shfl_up(x, off, 64);
        if (lane >= off) x += y;
    }
    int excl = x - s;
#pragma unroll
    for (int k = 0; k < 8; k++) {
        int id = lane * 8 + k;
        if (id <= NBKT) { gbase[id] = excl; if (id < NBKT) gcur[id] = excl; }
        excl += vals[k];
    }
    if (lane == 63) rowptr[RTOT] = x;   // total == ETOT
}

// ======================= degree-uniform row permutation =======================

__device__ __forceinline__ int seg_of_row(int r) {
    return (r < B1) ? 0 : (r < B2) ? 1 : (r < B3) ? 2 : (r < B4) ? 3 : 4;
}

__global__ void permhist_k(const int* __restrict__ rowptr, int* __restrict__ gbins) {
    __shared__ int h[PTOT];
    int tid = threadIdx.x;
    for (int i = tid; i < PTOT; i += 256) h[i] = 0;
    __syncthreads();
    int r = blockIdx.x * 256 + tid;
    if (r < RTOT) {
        int d = rowptr[r + 1] - rowptr[r];
        int bin = d < PBINS ? d : PBINS - 1;
        atomicAdd(&h[seg_of_row(r) * PBINS + bin], 1);
    }
    __syncthreads();
    for (int i = tid; i < PTOT; i += 256)
        if (h[i]) atomicAdd(&gbins[i], h[i]);
}

__global__ void permscan_k(int* __restrict__ gbins) {
    int lane = threadIdx.x;  // 64
    int vals[5];
    int s = 0;
#pragma unroll
    for (int k = 0; k < 5; k++) { vals[k] = gbins[lane * 5 + k]; s += vals[k]; }
    int x = s;
#pragma unroll
    for (int off = 1; off < 64; off <<= 1) {
        int y = __shfl_up(x, off, 64);
        if (lane >= off) x += y;
    }
    int excl = x - s;
#pragma unroll
    for (int k = 0; k < 5; k++) { gbins[lane * 5 + k] = excl; excl += vals[k]; }
}

__global__ __launch_bounds__(256) void permscat_k(const int* __restrict__ rowptr,
                                                  int* __restrict__ gbins,
                                                  int* __restrict__ perm) {
    __shared__ int h[PTOT], bs[PTOT], c2[PTOT];
    int tid = threadIdx.x;
    for (int i = tid; i < PTOT; i += 256) { h[i] = 0; c2[i] = 0; }
    __syncthreads();
    int r0 = blockIdx.x * 2048;
    int sb[8];
#pragma unroll
    for (int k = 0; k < 8; k++) {
        int r = r0 + k * 256 + tid;
        if (r < RTOT) {
            int d = rowptr[r + 1] - rowptr[r];
            int bin = d < PBINS ? d : PBINS - 1;
            sb[k] = seg_of_row(r) * PBINS + bin;
            atomicAdd(&h[sb[k]], 1);
        } else sb[k] = -1;
    }
    __syncthreads();
    for (int i = tid; i < PTOT; i += 256)
        if (h[i]) bs[i] = atomicAdd(&gbins[i], h[i]);
    __syncthreads();
#pragma unroll
    for (int k = 0; k < 8; k++) {
        if (sb[k] >= 0) {
            int r = r0 + k * 256 + tid;
            int loc = atomicAdd(&c2[sb[k]], 1);
            perm[bs[sb[k]] + loc] = r;
        }
    }
}

// ======================= edge binning =======================

__device__ __forceinline__ void decode_edge(int i,
        const int* __restrict__ ui_row, const int* __restrict__ ui_col,
        const int* __restrict__ ub_row, const int* __restrict__ ub_col,
        const int* __restrict__ bi_row, const int* __restrict__ bi_col,
        int E_UI, int E_UB, int E_BI, int& gdst, int& src) {
    if (i < E_UI)                     { gdst = B0 + ui_row[i]; src = ui_col[i]; }
    else if (i < 2 * E_UI)            { int j = i - E_UI; gdst = B1 + ui_col[j]; src = ui_row[j]; }
    else if (i < 2 * E_UI + E_UB)     { int j = i - 2 * E_UI; gdst = B2 + ub_row[j]; src = ub_col[j]; }
    else if (i < 2 * E_UI + 2 * E_UB) { int j = i - 2 * E_UI - E_UB; gdst = B3 + ub_col[j]; src = ub_row[j]; }
    else                              { int j = i - 2 * E_UI - 2 * E_UB; gdst = B4 + bi_row[j]; src = bi_col[j]; }
}

// Phase A: tile-local counting sort by coarse bucket; bbuf entry: (src<<10)|(gdst&1023)
// Edges decoded ONCE into registers; bucket scan wave-parallel (489 buckets).
__global__ __launch_bounds__(256) void binA_k(
        const int* __restrict__ ui_row, const int* __restrict__ ui_col,
        const int* __restrict__ ub_row, const int* __restrict__ ub_col,
        const int* __restrict__ bi_row, const int* __restrict__ bi_col,
        int E_UI, int E_UB, int E_BI, int ETOT,
        int* __restrict__ gcur, int* __restrict__ bbuf) {
    __shared__ int hist[NBKT], runStart[NBKT], gbase[NBKT], cnt2[NBKT];
    __shared__ int ord[TILE];
    __shared__ int gpos[TILE];
    int tid = threadIdx.x;
    for (int b = tid; b < NBKT; b += 256) { hist[b] = 0; cnt2[b] = 0; }
    __syncthreads();
    int base = blockIdx.x * TILE;
    int gd[EPT], sr[EPT];
#pragma unroll
    for (int k = 0; k < EPT; k++) {
        int i = base + k * 256 + tid;
        gd[k] = -1;
        if (i < ETOT) {
            decode_edge(i, ui_row, ui_col, ub_row, ub_col, bi_row, bi_col,
                        E_UI, E_UB, E_BI, gd[k], sr[k]);
            atomicAdd(&hist[gd[k] >> BKT_SHIFT], 1);
        }
    }
    __syncthreads();
    // wave-parallel exclusive scan of hist -> runStart (first 64 threads)
    if (tid < 64) {
        int vals[8];
        int ssum = 0;
#pragma unroll
        for (int k = 0; k < 8; k++) {
            int id = tid * 8 + k;
            vals[k] = (id < NBKT) ? hist[id] : 0;
            ssum += vals[k];
        }
        int x = ssum;
#pragma unroll
        for (int off = 1; off < 64; off <<= 1) {
            int y = __shfl_up(x, off, 64);
            if (tid >= off) x += y;
        }
        int excl = x - ssum;
#pragma unroll
        for (int k = 0; k < 8; k++) {
            int id = tid * 8 + k;
            if (id < NBKT) runStart[id] = excl;
            excl += vals[k];
        }
    }
    __syncthreads();
    for (int b = tid; b < NBKT; b += 256)
        if (hist[b] > 0) gbase[b] = atomicAdd(&gcur[b], hist[b]);
    __syncthreads();
#pragma unroll
    for (int k = 0; k < EPT; k++) {
        if (gd[k] >= 0) {
            int b = gd[k] >> BKT_SHIFT;
            int loc = runStart[b] + atomicAdd(&cnt2[b], 1);
            ord[loc] = (sr[k] << BKT_SHIFT) | (gd[k] & (ROWS_PER_BKT - 1));
            gpos[loc] = gbase[b] + (loc - runStart[b]);
        }
    }
    __syncthreads();
    int tcnt = runStart[NBKT - 1] + hist[NBKT - 1];
    for (int i = tid; i < tcnt; i += 256) bbuf[gpos[i]] = ord[i];
}

// Phase B: per-bucket row degree histogram + local scan -> writes rowptr AND
// places edges. 489 blocks x 1024 threads.
__global__ __launch_bounds__(1024) void binB_k(const int* __restrict__ gbase,
                                               const int* __restrict__ bbuf,
                                               int* __restrict__ rowptr,
                                               int* __restrict__ ebuf) {
    __shared__ int lh[ROWS_PER_BKT];   // histogram -> exclusive offsets -> cursors
    __shared__ int ws[16];
    int bkt = blockIdx.x;
    int tid = threadIdx.x;
    int s = gbase[bkt], e = gbase[bkt + 1];
    int rbase = bkt << BKT_SHIFT;
    int nrows = RTOT - rbase;
    if (nrows > ROWS_PER_BKT) nrows = ROWS_PER_BKT;
    lh[tid] = 0;
    __syncthreads();
    // pass 1: local degree histogram
    for (int i = s + tid; i < e; i += 1024)
        atomicAdd(&lh[bbuf[i] & (ROWS_PER_BKT - 1)], 1);
    __syncthreads();
    // block exclusive scan of 1024 entries (1 per thread)
    int v = lh[tid];
    int lane = tid & 63, w = tid >> 6;
    int x = v;
#pragma unroll
    for (int off = 1; off < 64; off <<= 1) {
        int y = __shfl_up(x, off, 64);
        if (lane >= off) x += y;
    }
    if (lane == 63) ws[w] = x;
    __syncthreads();
    if (tid == 0) {
        int run = 0;
#pragma unroll
        for (int k = 0; k < 16; k++) { int t = ws[k]; ws[k] = run; run += t; }
    }
    __syncthreads();
    int p = s + ws[w] + (x - v);   // exclusive offset for row tid
    lh[tid] = p;
    if (tid < nrows) rowptr[rbase + tid] = p;
    __syncthreads();
    // pass 2: place edges
    for (int i = s + tid; i < e; i += 1024) {
        int entry = bbuf[i];
        int r = entry & (ROWS_PER_BKT - 1);
        int pos = atomicAdd(&lh[r], 1);
        ebuf[pos] = (entry >> BKT_SHIFT) << 7;
    }
}

// ======================= pull machinery (bf16, 8 lanes/row) =======================
// wave = 8 rows; lane l: group = l>>3 (row), q = (l&7)*16B (8 dims as bf16x8).
// 8-deep gather pipeline: 8 independent offset loads -> 8 independent 16B
// gathers in flight -> 8 accumulates. Doubles MLP vs the old 4-deep loop
// (stage pulls were latency-bound: 46% HBM-path, 24% VALU, 69% occ).

__device__ __forceinline__ void pull8(int s, int e, const int* __restrict__ ebuf,
                                      const char* __restrict__ baseq, float* a) {
    int j = s;
    for (; j + 7 < e; j += 8) {
        int c0 = ebuf[j],     c1 = ebuf[j + 1], c2 = ebuf[j + 2], c3 = ebuf[j + 3];
        int c4 = ebuf[j + 4], c5 = ebuf[j + 5], c6 = ebuf[j + 6], c7 = ebuf[j + 7];
        uint4 v0 = *reinterpret_cast<const uint4*>(baseq + c0);
        uint4 v1 = *reinterpret_cast<const uint4*>(baseq + c1);
        uint4 v2 = *reinterpret_cast<const uint4*>(baseq + c2);
        uint4 v3 = *reinterpret_cast<const uint4*>(baseq + c3);
        uint4 v4 = *reinterpret_cast<const uint4*>(baseq + c4);
        uint4 v5 = *reinterpret_cast<const uint4*>(baseq + c5);
        uint4 v6 = *reinterpret_cast<const uint4*>(baseq + c6);
        uint4 v7 = *reinterpret_cast<const uint4*>(baseq + c7);
        addbf8(v0, a); addbf8(v1, a); addbf8(v2, a); addbf8(v3, a);
        addbf8(v4, a); addbf8(v5, a); addbf8(v6, a); addbf8(v7, a);
    }
    for (; j + 3 < e; j += 4) {
        int c0 = ebuf[j], c1 = ebuf[j + 1], c2 = ebuf[j + 2], c3 = ebuf[j + 3];
        uint4 v0 = *reinterpret_cast<const uint4*>(baseq + c0);
        uint4 v1 = *reinterpret_cast<const uint4*>(baseq + c1);
        uint4 v2 = *reinterpret_cast<const uint4*>(baseq + c2);
        uint4 v3 = *reinterpret_cast<const uint4*>(baseq + c3);
        addbf8(v0, a); addbf8(v1, a); addbf8(v2, a); addbf8(v3, a);
    }
    for (; j < e; ++j) {
        uint4 v = *reinterpret_cast<const uint4*>(baseq + ebuf[j]);
        addbf8(v, a);
    }
}

__device__ __forceinline__ float rowsum8(float s) {
    s += __shfl_xor(s, 1, 64);
    s += __shfl_xor(s, 2, 64);
    s += __shfl_xor(s, 4, 64);
    return s;
}

// stage1: all four layer-1 pulls fused; bf16 in, bf16 out, no cross-lane needed
__global__ void stage1_k(const int* __restrict__ rowptr, const int* __restrict__ ebuf,
                         const int* __restrict__ perm,
                         const ushort_t* __restrict__ Ubh, const ushort_t* __restrict__ Ibh,
                         const ushort_t* __restrict__ Bbh,
                         ushort_t* __restrict__ f1u_ui, ushort_t* __restrict__ f1i_ui,
                         ushort_t* __restrict__ f1u_ub, ushort_t* __restrict__ f1b_ub) {
    int gr0 = blockIdx.x * 32 + (threadIdx.x >> 3);
    if (gr0 >= B4) return;
    int gr = perm[gr0];
    int q = (threadIdx.x & 7) << 4;
    const ushort_t* src; ushort_t* dst; int row;
    if (gr < B1)      { src = Ibh; dst = f1u_ui; row = gr; }
    else if (gr < B2) { src = Ubh; dst = f1i_ui; row = gr - B1; }
    else if (gr < B3) { src = Bbh; dst = f1u_ub; row = gr - B2; }
    else              { src = Ubh; dst = f1b_ub; row = gr - B3; }
    int s = rowptr[gr], e = rowptr[gr + 1];
    float a[8] = {0, 0, 0, 0, 0, 0, 0, 0};
    pull8(s, e, ebuf, (const char*)src + q, a);
    *reinterpret_cast<uint4*>((char*)dst + (size_t)row * 128 + q) = pack8(a);
}

// finalize: out(f32) = base + l2norm(self) + l2norm(acc)
__device__ __forceinline__ void fin8_f32(const float* a, const ushort_t* selfbh,
                                         const float* basef, float* out, int row, int l) {
    int q = l << 4;
    uint4 sv = *reinterpret_cast<const uint4*>((const char*)selfbh + (size_t)row * 128 + q);
    float v[8] = {0, 0, 0, 0, 0, 0, 0, 0};
    addbf8(sv, v);
    float s1 = 0.f, s2 = 0.f;
#pragma unroll
    for (int k = 0; k < 8; k++) { s1 = fmaf(v[k], v[k], s1); s2 = fmaf(a[k], a[k], s2); }
    s1 = rowsum8(s1);
    s2 = rowsum8(s2);
    float i1 = 1.0f / fmaxf(sqrtf(s1), 1e-12f);
    float i2 = 1.0f / fmaxf(sqrtf(s2), 1e-12f);
    const float4 b0 = *reinterpret_cast<const float4*>(basef + (size_t)row * D + l * 8);
    const float4 b1 = *reinterpret_cast<const float4*>(basef + (size_t)row * D + l * 8 + 4);
    float4 o0, o1;
    o0.x = b0.x + v[0] * i1 + a[0] * i2;
    o0.y = b0.y + v[1] * i1 + a[1] * i2;
    o0.z = b0.z + v[2] * i1 + a[2] * i2;
    o0.w = b0.w + v[3] * i1 + a[3] * i2;
    o1.x = b1.x + v[4] * i1 + a[4] * i2;
    o1.y = b1.y + v[5] * i1 + a[5] * i2;
    o1.z = b1.z + v[6] * i1 + a[6] * i2;
    o1.w = b1.w + v[7] * i1 + a[7] * i2;
    *reinterpret_cast<float4*>(out + (size_t)row * 128 + l * 8) = o0;
    *reinterpret_cast<float4*>(out + (size_t)row * 128 + l * 8 + 4) = o1;
}

// stage2a: ui-user, ub-user, ub-bundle finalize fused -> f32 outputs
__global__ void stage2a_k(const int* __restrict__ rowptr, const int* __restrict__ ebuf,
                          const int* __restrict__ perm,
                          const float* __restrict__ U, const float* __restrict__ Bf,
                          const ushort_t* __restrict__ f1u_ui, const ushort_t* __restrict__ f1i_ui,
                          const ushort_t* __restrict__ f1u_ub, const ushort_t* __restrict__ f1b_ub,
                          float* __restrict__ outU, float* __restrict__ outB) {
    int t = blockIdx.x * 32 + (threadIdx.x >> 3);
    if (t >= 2 * NU + NB) return;
    int l = threadIdx.x & 7;
    int cr, row; const ushort_t* src; const ushort_t* self; const float* basef; float* out;
    if (t < NU)          { cr = perm[t];               src = f1i_ui; self = f1u_ui; basef = U;  out = outU;      row = cr; }
    else if (t < 2 * NU) { cr = perm[B2 + t - NU];     src = f1b_ub; self = f1u_ub; basef = U;  out = outU + 64; row = cr - B2; }
    else                 { cr = perm[B3 + t - 2 * NU]; src = f1u_ub; self = f1b_ub; basef = Bf; out = outB + 64; row = cr - B3; }
    int q = l << 4;
    int s = rowptr[cr], e = rowptr[cr + 1];
    float a[8] = {0, 0, 0, 0, 0, 0, 0, 0};
    pull8(s, e, ebuf, (const char*)src + q, a);
    fin8_f32(a, self, basef, out, row, l);
}

// stage2b: ui-item finalize; acc_i written IN PLACE (bf16) over f1i_ui
__global__ void stage2b_k(const int* __restrict__ rowptr, const int* __restrict__ ebuf,
                          const int* __restrict__ perm,
                          const float* __restrict__ I, const ushort_t* __restrict__ f1u_ui,
                          ushort_t* __restrict__ f1i_ui) {
    int t = blockIdx.x * 32 + (threadIdx.x >> 3);
    if (t >= NI) return;
    int l = threadIdx.x & 7;
    int q = l << 4;
    int cr = perm[B1 + t];
    int row = cr - B1;
    int s = rowptr[cr], e = rowptr[cr + 1];
    float a[8] = {0, 0, 0, 0, 0, 0, 0, 0};
    pull8(s, e, ebuf, (const char*)f1u_ui + q, a);
    uint4 sv = *reinterpret_cast<const uint4*>((const char*)f1i_ui + (size_t)row * 128 + q);
    float v[8] = {0, 0, 0, 0, 0, 0, 0, 0};
    addbf8(sv, v);
    float s1 = 0.f, s2 = 0.f;
#pragma unroll
    for (int k = 0; k < 8; k++) { s1 = fmaf(v[k], v[k], s1); s2 = fmaf(a[k], a[k], s2); }
    s1 = rowsum8(s1);
    s2 = rowsum8(s2);
    float i1 = 1.0f / fmaxf(sqrtf(s1), 1e-12f);
    float i2 = 1.0f / fmaxf(sqrtf(s2), 1e-12f);
    const float4 b0 = *reinterpret_cast<const float4*>(I + (size_t)row * D + l * 8);
    const float4 b1 = *reinterpret_cast<const float4*>(I + (size_t)row * D + l * 8 + 4);
    float o[8];
    o[0] = b0.x + v[0] * i1 + a[0] * i2;
    o[1] = b0.y + v[1] * i1 + a[1] * i2;
    o[2] = b0.z + v[2] * i1 + a[2] * i2;
    o[3] = b0.w + v[3] * i1 + a[3] * i2;
    o[4] = b1.x + v[4] * i1 + a[4] * i2;
    o[5] = b1.y + v[5] * i1 + a[5] * i2;
    o[6] = b1.z + v[6] * i1 + a[6] * i2;
    o[7] = b1.w + v[7] * i1 + a[7] * i2;
    *reinterpret_cast<uint4*>((char*)f1i_ui + (size_t)row * 128 + q) = pack8(o);
}

// stage3: weighted bi aggregation from bf16 acc_i -> outB[:,0:64] (f32)
__global__ void stage3_k(const int* __restrict__ rowptr, const int* __restrict__ ebuf,
                         const int* __restrict__ perm,
                         const ushort_t* __restrict__ acc_i, float* __restrict__ outB) {
    int t = blockIdx.x * 32 + (threadIdx.x >> 3);
    if (t >= NB) return;
    int l = threadIdx.x & 7;
    int q = l << 4;
    int cr = perm[B4 + t];
    int row = cr - B4;
    int s = rowptr[cr], e = rowptr[cr + 1];
    float a[8] = {0, 0, 0, 0, 0, 0, 0, 0};
    pull8(s, e, ebuf, (const char*)acc_i + q, a);
    float w = 1.0f / ((float)(e - s) + 1e-8f);
    float4 o0 = {a[0] * w, a[1] * w, a[2] * w, a[3] * w};
    float4 o1 = {a[4] * w, a[5] * w, a[6] * w, a[7] * w};
    *reinterpret_cast<float4*>(outB + (size_t)row * 128 + l * 8) = o0;
    *reinterpret_cast<float4*>(outB + (size_t)row * 128 + l * 8 + 4) = o1;
}

extern "C" void kernel_launch(void* const* d_in, const int* in_sizes, int n_in,
                              void* d_out, int out_size, void* d_ws, size_t ws_size,
                              hipStream_t stream) {
    const float* U = (const float*)d_in[0];
    const float* I = (const float*)d_in[1];
    const float* B = (const float*)d_in[2];
    const int* ui_row = (const int*)d_in[3];
    const int* ui_col = (const int*)d_in[4];
    const int* ub_row = (const int*)d_in[5];
    const int* ub_col = (const int*)d_in[6];
    const int* bi_row = (const int*)d_in[7];
    const int* bi_col = (const int*)d_in[8];
    const int E_UI = in_sizes[3], E_UB = in_sizes[5], E_BI = in_sizes[7];
    const int ETOT = 2 * E_UI + 2 * E_UB + E_BI;

    // workspace layout (~146 MB): bf16 tables + bf16 intermediates + CSR + perm
    ushort_t* Ubh    = (ushort_t*)d_ws;                 // NU*D
    ushort_t* Ibh    = Ubh + (size_t)NU * D;            // NI*D
    ushort_t* Bbh    = Ibh + (size_t)NI * D;            // NB*D
    ushort_t* f1u_ui = Bbh + (size_t)NB * D;            // NU*D
    ushort_t* f1i_ui = f1u_ui + (size_t)NU * D;         // NI*D (becomes acc_i)
    ushort_t* f1u_ub = f1i_ui + (size_t)NI * D;         // NU*D
    ushort_t* f1b_ub = f1u_ub + (size_t)NU * D;         // NB*D
    int* rowptr    = (int*)(f1b_ub + (size_t)NB * D);   // RTOT+1
    int* gcur      = rowptr + (RTOT + 1);               // NBKT_PAD (512)
    int* gbase     = gcur + NBKT_PAD;                   // NBKT_PAD (512, uses NBKT+1)
    int* gbins     = gbase + NBKT_PAD;                  // PTOT (320)
    int* ebuf      = gbins + PTOT;                      // ETOT
    int* bbuf      = ebuf + ETOT;                       // ETOT
    int* perm      = bbuf + ETOT;                       // RTOT

    float* outU = (float*)d_out;            // NU x 128 (IL_u | BL_u)
    float* outB = outU + (size_t)NU * 128;  // NB x 128 (IL_b | BL_b)

    const int T = 256;
    const int NCVT = (NU + NI + NB) * D / 8;

    // ---- bf16 table conversion ----
    cvt_all_k<<<(NCVT + T - 1) / T, T, 0, stream>>>(U, I, B, Ubh, Ibh, Bbh);

    // ---- bucket-level CSR build ----
    hipMemsetAsync(gbase, 0, (NBKT_PAD + PTOT) * sizeof(int), stream);  // gbase + gbins
    bhist_k<<<1280, T, 0, stream>>>(ui_row, ui_col, ub_row, ub_col, bi_row,
                                    E_UI, E_UB, E_BI, ETOT, gbase);
    bscan_k<<<1, 64, 0, stream>>>(gbase, gcur, rowptr);

    // ---- edge binning (binB also derives per-row rowptr locally) ----
    binA_k<<<(ETOT + TILE - 1) / TILE, 256, 0, stream>>>(ui_row, ui_col, ub_row, ub_col,
                                                         bi_row, bi_col, E_UI, E_UB, E_BI,
                                                         ETOT, gcur, bbuf);
    binB_k<<<NBKT, 1024, 0, stream>>>(gbase, bbuf, rowptr, ebuf);

    // ---- degree-uniform row permutation (removes pull-loop divergence) ----
    permhist_k<<<(RTOT + 255) / 256, 256, 0, stream>>>(rowptr, gbins);
    permscan_k<<<1, 64, 0, stream>>>(gbins);
    permscat_k<<<(RTOT + 2047) / 2048, 256, 0, stream>>>(rowptr, gbins, perm);

    // ---- stage1: all four layer-1 pulls ----
    stage1_k<<<(B4 + 31) / 32, T, 0, stream>>>(rowptr, ebuf, perm, Ubh, Ibh, Bbh,
                                               f1u_ui, f1i_ui, f1u_ub, f1b_ub);
    // ---- stage2a: ui-user, ub-user, ub-bundle finalize ----
    stage2a_k<<<(2 * NU + NB + 31) / 32, T, 0, stream>>>(rowptr, ebuf, perm, U, B,
                                                         f1u_ui, f1i_ui, f1u_ub, f1b_ub,
                                                         outU, outB);
    // ---- stage2b: ui-item finalize (in-place bf16 acc_i) ----
    stage2b_k<<<(NI + 31) / 32, T, 0, stream>>>(rowptr, ebuf, perm, I, f1u_ui, f1i_ui);
    // ---- stage3: weighted bi aggregation ----
    stage3_k<<<(NB + 31) / 32, T, 0, stream>>>(rowptr, ebuf, perm, f1i_ui, outB);
}

// Round 11
// 456.731 us; speedup vs baseline: 1.4532x; 1.0317x over previous
//
#include <hip/hip_runtime.h>
#include <hip/hip_bf16.h>

// Problem constants (match reference setup_inputs)
#define NU 100000
#define NI 200000
#define NB 50000
#define D  64

// Concatenated CSR row-space: 5 graph directions
#define B0 0
#define B1 (NU)
#define B2 (NU + NI)
#define B3 (2 * NU + NI)
#define B4 (2 * NU + NI + NB)
#define RTOT (2 * NU + NI + 2 * NB)   // 500000 rows total

// Bucketing for the two-phase edge sort
// BKT_SHIFT=10: 489 buckets -> binB grid covers all 256 CUs.
#define BKT_SHIFT 10
#define ROWS_PER_BKT 1024
#define NBKT ((RTOT + ROWS_PER_BKT - 1) / ROWS_PER_BKT)   // 489
#define NBKT_PAD 512
#define TILE 4096
#define EPT (TILE / 256)

typedef unsigned short ushort_t;

// ======================= bf16 helpers =======================

__device__ __forceinline__ unsigned f2bf(float f) {
    unsigned u = __float_as_uint(f);
    return (u + 0x7FFFu + ((u >> 16) & 1u)) >> 16;   // RNE
}

__device__ __forceinline__ uint4 pack8(const float* a) {
    uint4 o;
    o.x = f2bf(a[0]) | (f2bf(a[1]) << 16);
    o.y = f2bf(a[2]) | (f2bf(a[3]) << 16);
    o.z = f2bf(a[4]) | (f2bf(a[5]) << 16);
    o.w = f2bf(a[6]) | (f2bf(a[7]) << 16);
    return o;
}

__device__ __forceinline__ void addbf8(uint4 v, float* a) {
    a[0] += __uint_as_float(v.x << 16);
    a[1] += __uint_as_float(v.x & 0xFFFF0000u);
    a[2] += __uint_as_float(v.y << 16);
    a[3] += __uint_as_float(v.y & 0xFFFF0000u);
    a[4] += __uint_as_float(v.z << 16);
    a[5] += __uint_as_float(v.z & 0xFFFF0000u);
    a[6] += __uint_as_float(v.w << 16);
    a[7] += __uint_as_float(v.w & 0xFFFF0000u);
}

// f32 tables -> bf16 tables (one fused launch; 8 elems/thread)
__global__ void cvt_all_k(const float* __restrict__ U, const float* __restrict__ I,
                          const float* __restrict__ Bf,
                          ushort_t* __restrict__ Ubh, ushort_t* __restrict__ Ibh,
                          ushort_t* __restrict__ Bbh) {
    int t = blockIdx.x * blockDim.x + threadIdx.x;
    const int nU = NU * D / 8, nI = NI * D / 8, nB = NB * D / 8;
    const float* s; ushort_t* d;
    if (t < nU)           { s = U;  d = Ubh; }
    else if (t < nU + nI) { s = I;  d = Ibh; t -= nU; }
    else if (t < nU + nI + nB) { s = Bf; d = Bbh; t -= nU + nI; }
    else return;
    const float4 f0 = *reinterpret_cast<const float4*>(s + (size_t)t * 8);
    const float4 f1 = *reinterpret_cast<const float4*>(s + (size_t)t * 8 + 4);
    float a[8] = {f0.x, f0.y, f0.z, f0.w, f1.x, f1.y, f1.z, f1.w};
    *reinterpret_cast<uint4*>(d + (size_t)t * 8) = pack8(a);
}

// ======================= bucket histogram =======================

__global__ __launch_bounds__(256) void bhist_k(
        const int* __restrict__ ui_row, const int* __restrict__ ui_col,
        const int* __restrict__ ub_row, const int* __restrict__ ub_col,
        const int* __restrict__ bi_row,
        int E_UI, int E_UB, int E_BI, int ETOT, int* __restrict__ gbase) {
    __shared__ int h[NBKT];
    int tid = threadIdx.x;
    for (int b = tid; b < NBKT; b += 256) h[b] = 0;
    __syncthreads();
    for (int i = blockIdx.x * 256 + tid; i < ETOT; i += gridDim.x * 256) {
        int gdst;
        if (i < E_UI)                     gdst = B0 + ui_row[i];
        else if (i < 2 * E_UI)            gdst = B1 + ui_col[i - E_UI];
        else if (i < 2 * E_UI + E_UB)     gdst = B2 + ub_row[i - 2 * E_UI];
        else if (i < 2 * E_UI + 2 * E_UB) gdst = B3 + ub_col[i - 2 * E_UI - E_UB];
        else                              gdst = B4 + bi_row[i - 2 * E_UI - 2 * E_UB];
        atomicAdd(&h[gdst >> BKT_SHIFT], 1);
    }
    __syncthreads();
    for (int b = tid; b < NBKT; b += 256)
        if (h[b]) atomicAdd(&gbase[b], h[b]);
}

// one-wave exclusive scan of the 489 bucket counts -> gbase (bases), gcur copy.
__global__ void bscan_k(int* __restrict__ gbase, int* __restrict__ gcur,
                        int* __restrict__ rowptr) {
    int lane = threadIdx.x;  // 64
    int vals[8];
    int s = 0;
#pragma unroll
    for (int k = 0; k < 8; k++) {
        int id = lane * 8 + k;
        vals[k] = (id < NBKT) ? gbase[id] : 0;
        s += vals[k];
    }
    int x = s;
#pragma unroll
    for (int off = 1; off < 64; off <<= 1) {
        int y = __shfl_up(x, off, 64);
        if (lane >= off) x += y;
    }
    int excl = x - s;
#pragma unroll
    for (int k = 0; k < 8; k++) {
        int id = lane * 8 + k;
        if (id <= NBKT) { gbase[id] = excl; if (id < NBKT) gcur[id] = excl; }
        excl += vals[k];
    }
    if (lane == 63) rowptr[RTOT] = x;   // total == ETOT
}

// ======================= edge binning =======================

__device__ __forceinline__ void decode_edge(int i,
        const int* __restrict__ ui_row, const int* __restrict__ ui_col,
        const int* __restrict__ ub_row, const int* __restrict__ ub_col,
        const int* __restrict__ bi_row, const int* __restrict__ bi_col,
        int E_UI, int E_UB, int E_BI, int& gdst, int& src) {
    if (i < E_UI)                     { gdst = B0 + ui_row[i]; src = ui_col[i]; }
    else if (i < 2 * E_UI)            { int j = i - E_UI; gdst = B1 + ui_col[j]; src = ui_row[j]; }
    else if (i < 2 * E_UI + E_UB)     { int j = i - 2 * E_UI; gdst = B2 + ub_row[j]; src = ub_col[j]; }
    else if (i < 2 * E_UI + 2 * E_UB) { int j = i - 2 * E_UI - E_UB; gdst = B3 + ub_col[j]; src = ub_row[j]; }
    else                              { int j = i - 2 * E_UI - 2 * E_UB; gdst = B4 + bi_row[j]; src = bi_col[j]; }
}

// Phase A: tile-local counting sort by coarse bucket; bbuf entry: (src<<10)|(gdst&1023)
// Edges decoded ONCE into registers; bucket scan wave-parallel (489 buckets).
__global__ __launch_bounds__(256) void binA_k(
        const int* __restrict__ ui_row, const int* __restrict__ ui_col,
        const int* __restrict__ ub_row, const int* __restrict__ ub_col,
        const int* __restrict__ bi_row, const int* __restrict__ bi_col,
        int E_UI, int E_UB, int E_BI, int ETOT,
        int* __restrict__ gcur, int* __restrict__ bbuf) {
    __shared__ int hist[NBKT], runStart[NBKT], gbase[NBKT], cnt2[NBKT];
    __shared__ int ord[TILE];
    __shared__ int gpos[TILE];
    int tid = threadIdx.x;
    for (int b = tid; b < NBKT; b += 256) { hist[b] = 0; cnt2[b] = 0; }
    __syncthreads();
    int base = blockIdx.x * TILE;
    int gd[EPT], sr[EPT];
#pragma unroll
    for (int k = 0; k < EPT; k++) {
        int i = base + k * 256 + tid;
        gd[k] = -1;
        if (i < ETOT) {
            decode_edge(i, ui_row, ui_col, ub_row, ub_col, bi_row, bi_col,
                        E_UI, E_UB, E_BI, gd[k], sr[k]);
            atomicAdd(&hist[gd[k] >> BKT_SHIFT], 1);
        }
    }
    __syncthreads();
    // wave-parallel exclusive scan of hist -> runStart (first 64 threads)
    if (tid < 64) {
        int vals[8];
        int ssum = 0;
#pragma unroll
        for (int k = 0; k < 8; k++) {
            int id = tid * 8 + k;
            vals[k] = (id < NBKT) ? hist[id] : 0;
            ssum += vals[k];
        }
        int x = ssum;
#pragma unroll
        for (int off = 1; off < 64; off <<= 1) {
            int y = __shfl_up(x, off, 64);
            if (tid >= off) x += y;
        }
        int excl = x - ssum;
#pragma unroll
        for (int k = 0; k < 8; k++) {
            int id = tid * 8 + k;
            if (id < NBKT) runStart[id] = excl;
            excl += vals[k];
        }
    }
    __syncthreads();
    for (int b = tid; b < NBKT; b += 256)
        if (hist[b] > 0) gbase[b] = atomicAdd(&gcur[b], hist[b]);
    __syncthreads();
#pragma unroll
    for (int k = 0; k < EPT; k++) {
        if (gd[k] >= 0) {
            int b = gd[k] >> BKT_SHIFT;
            int loc = runStart[b] + atomicAdd(&cnt2[b], 1);
            ord[loc] = (sr[k] << BKT_SHIFT) | (gd[k] & (ROWS_PER_BKT - 1));
            gpos[loc] = gbase[b] + (loc - runStart[b]);
        }
    }
    __syncthreads();
    int tcnt = runStart[NBKT - 1] + hist[NBKT - 1];
    for (int i = tid; i < tcnt; i += 256) bbuf[gpos[i]] = ord[i];
}

// Phase B: per-bucket row degree histogram + local scan -> writes rowptr AND
// places edges. 489 blocks x 1024 threads.
__global__ __launch_bounds__(1024) void binB_k(const int* __restrict__ gbase,
                                               const int* __restrict__ bbuf,
                                               int* __restrict__ rowptr,
                                               int* __restrict__ ebuf) {
    __shared__ int lh[ROWS_PER_BKT];   // histogram -> exclusive offsets -> cursors
    __shared__ int ws[16];
    int bkt = blockIdx.x;
    int tid = threadIdx.x;
    int s = gbase[bkt], e = gbase[bkt + 1];
    int rbase = bkt << BKT_SHIFT;
    int nrows = RTOT - rbase;
    if (nrows > ROWS_PER_BKT) nrows = ROWS_PER_BKT;
    lh[tid] = 0;
    __syncthreads();
    // pass 1: local degree histogram
    for (int i = s + tid; i < e; i += 1024)
        atomicAdd(&lh[bbuf[i] & (ROWS_PER_BKT - 1)], 1);
    __syncthreads();
    // block exclusive scan of 1024 entries (1 per thread)
    int v = lh[tid];
    int lane = tid & 63, w = tid >> 6;
    int x = v;
#pragma unroll
    for (int off = 1; off < 64; off <<= 1) {
        int y = __shfl_up(x, off, 64);
        if (lane >= off) x += y;
    }
    if (lane == 63) ws[w] = x;
    __syncthreads();
    if (tid == 0) {
        int run = 0;
#pragma unroll
        for (int k = 0; k < 16; k++) { int t = ws[k]; ws[k] = run; run += t; }
    }
    __syncthreads();
    int p = s + ws[w] + (x - v);   // exclusive offset for row tid
    lh[tid] = p;
    if (tid < nrows) rowptr[rbase + tid] = p;
    __syncthreads();
    // pass 2: place edges
    for (int i = s + tid; i < e; i += 1024) {
        int entry = bbuf[i];
        int r = entry & (ROWS_PER_BKT - 1);
        int pos = atomicAdd(&lh[r], 1);
        ebuf[pos] = (entry >> BKT_SHIFT) << 7;
    }
}

// ======================= pull machinery (bf16, 8 lanes/row) =======================
// wave = 8 rows; lane l: group = l>>3 (row), q = (l&7)*16B (8 dims as bf16x8).
// Rows visited in NATURAL order (perm dropped: counters show pulls are
// latency/BW-bound, VALUBusy 25% -> divergence is cheap; natural order gives
// contiguous rowptr/ebuf reads and coalesced self/base/out rows).

__device__ __forceinline__ void pull8(int s, int e, const int* __restrict__ ebuf,
                                      const char* __restrict__ baseq, float* a) {
    int j = s;
    for (; j + 7 < e; j += 8) {
        int c0 = ebuf[j],     c1 = ebuf[j + 1], c2 = ebuf[j + 2], c3 = ebuf[j + 3];
        int c4 = ebuf[j + 4], c5 = ebuf[j + 5], c6 = ebuf[j + 6], c7 = ebuf[j + 7];
        uint4 v0 = *reinterpret_cast<const uint4*>(baseq + c0);
        uint4 v1 = *reinterpret_cast<const uint4*>(baseq + c1);
        uint4 v2 = *reinterpret_cast<const uint4*>(baseq + c2);
        uint4 v3 = *reinterpret_cast<const uint4*>(baseq + c3);
        uint4 v4 = *reinterpret_cast<const uint4*>(baseq + c4);
        uint4 v5 = *reinterpret_cast<const uint4*>(baseq + c5);
        uint4 v6 = *reinterpret_cast<const uint4*>(baseq + c6);
        uint4 v7 = *reinterpret_cast<const uint4*>(baseq + c7);
        addbf8(v0, a); addbf8(v1, a); addbf8(v2, a); addbf8(v3, a);
        addbf8(v4, a); addbf8(v5, a); addbf8(v6, a); addbf8(v7, a);
    }
    for (; j + 3 < e; j += 4) {
        int c0 = ebuf[j], c1 = ebuf[j + 1], c2 = ebuf[j + 2], c3 = ebuf[j + 3];
        uint4 v0 = *reinterpret_cast<const uint4*>(baseq + c0);
        uint4 v1 = *reinterpret_cast<const uint4*>(baseq + c1);
        uint4 v2 = *reinterpret_cast<const uint4*>(baseq + c2);
        uint4 v3 = *reinterpret_cast<const uint4*>(baseq + c3);
        addbf8(v0, a); addbf8(v1, a); addbf8(v2, a); addbf8(v3, a);
    }
    for (; j < e; ++j) {
        uint4 v = *reinterpret_cast<const uint4*>(baseq + ebuf[j]);
        addbf8(v, a);
    }
}

__device__ __forceinline__ float rowsum8(float s) {
    s += __shfl_xor(s, 1, 64);
    s += __shfl_xor(s, 2, 64);
    s += __shfl_xor(s, 4, 64);
    return s;
}

// stage1: all four layer-1 pulls fused; bf16 in, bf16 out, no cross-lane needed
__global__ void stage1_k(const int* __restrict__ rowptr, const int* __restrict__ ebuf,
                         const ushort_t* __restrict__ Ubh, const ushort_t* __restrict__ Ibh,
                         const ushort_t* __restrict__ Bbh,
                         ushort_t* __restrict__ f1u_ui, ushort_t* __restrict__ f1i_ui,
                         ushort_t* __restrict__ f1u_ub, ushort_t* __restrict__ f1b_ub) {
    int gr = blockIdx.x * 32 + (threadIdx.x >> 3);
    if (gr >= B4) return;
    int q = (threadIdx.x & 7) << 4;
    const ushort_t* src; ushort_t* dst; int row;
    if (gr < B1)      { src = Ibh; dst = f1u_ui; row = gr; }
    else if (gr < B2) { src = Ubh; dst = f1i_ui; row = gr - B1; }
    else if (gr < B3) { src = Bbh; dst = f1u_ub; row = gr - B2; }
    else              { src = Ubh; dst = f1b_ub; row = gr - B3; }
    int s = rowptr[gr], e = rowptr[gr + 1];
    float a[8] = {0, 0, 0, 0, 0, 0, 0, 0};
    pull8(s, e, ebuf, (const char*)src + q, a);
    *reinterpret_cast<uint4*>((char*)dst + (size_t)row * 128 + q) = pack8(a);
}

// finalize: out(f32) = base + l2norm(self) + l2norm(acc)
__device__ __forceinline__ void fin8_f32(const float* a, const ushort_t* selfbh,
                                         const float* basef, float* out, int row, int l) {
    int q = l << 4;
    uint4 sv = *reinterpret_cast<const uint4*>((const char*)selfbh + (size_t)row * 128 + q);
    float v[8] = {0, 0, 0, 0, 0, 0, 0, 0};
    addbf8(sv, v);
    float s1 = 0.f, s2 = 0.f;
#pragma unroll
    for (int k = 0; k < 8; k++) { s1 = fmaf(v[k], v[k], s1); s2 = fmaf(a[k], a[k], s2); }
    s1 = rowsum8(s1);
    s2 = rowsum8(s2);
    float i1 = 1.0f / fmaxf(sqrtf(s1), 1e-12f);
    float i2 = 1.0f / fmaxf(sqrtf(s2), 1e-12f);
    const float4 b0 = *reinterpret_cast<const float4*>(basef + (size_t)row * D + l * 8);
    const float4 b1 = *reinterpret_cast<const float4*>(basef + (size_t)row * D + l * 8 + 4);
    float4 o0, o1;
    o0.x = b0.x + v[0] * i1 + a[0] * i2;
    o0.y = b0.y + v[1] * i1 + a[1] * i2;
    o0.z = b0.z + v[2] * i1 + a[2] * i2;
    o0.w = b0.w + v[3] * i1 + a[3] * i2;
    o1.x = b1.x + v[4] * i1 + a[4] * i2;
    o1.y = b1.y + v[5] * i1 + a[5] * i2;
    o1.z = b1.z + v[6] * i1 + a[6] * i2;
    o1.w = b1.w + v[7] * i1 + a[7] * i2;
    *reinterpret_cast<float4*>(out + (size_t)row * 128 + l * 8) = o0;
    *reinterpret_cast<float4*>(out + (size_t)row * 128 + l * 8 + 4) = o1;
}

// stage2a: ui-user, ub-user, ub-bundle finalize fused -> f32 outputs
__global__ void stage2a_k(const int* __restrict__ rowptr, const int* __restrict__ ebuf,
                          const float* __restrict__ U, const float* __restrict__ Bf,
                          const ushort_t* __restrict__ f1u_ui, const ushort_t* __restrict__ f1i_ui,
                          const ushort_t* __restrict__ f1u_ub, const ushort_t* __restrict__ f1b_ub,
                          float* __restrict__ outU, float* __restrict__ outB) {
    int t = blockIdx.x * 32 + (threadIdx.x >> 3);
    if (t >= 2 * NU + NB) return;
    int l = threadIdx.x & 7;
    int cr, row; const ushort_t* src; const ushort_t* self; const float* basef; float* out;
    if (t < NU)          { cr = t;               src = f1i_ui; self = f1u_ui; basef = U;  out = outU;      row = t; }
    else if (t < 2 * NU) { cr = B2 + t - NU;     src = f1b_ub; self = f1u_ub; basef = U;  out = outU + 64; row = t - NU; }
    else                 { cr = B3 + t - 2 * NU; src = f1u_ub; self = f1b_ub; basef = Bf; out = outB + 64; row = t - 2 * NU; }
    int q = l << 4;
    int s = rowptr[cr], e = rowptr[cr + 1];
    float a[8] = {0, 0, 0, 0, 0, 0, 0, 0};
    pull8(s, e, ebuf, (const char*)src + q, a);
    fin8_f32(a, self, basef, out, row, l);
}

// stage2b: ui-item finalize; acc_i written IN PLACE (bf16) over f1i_ui
__global__ void stage2b_k(const int* __restrict__ rowptr, const int* __restrict__ ebuf,
                          const float* __restrict__ I, const ushort_t* __restrict__ f1u_ui,
                          ushort_t* __restrict__ f1i_ui) {
    int t = blockIdx.x * 32 + (threadIdx.x >> 3);
    if (t >= NI) return;
    int l = threadIdx.x & 7;
    int q = l << 4;
    int s = rowptr[B1 + t], e = rowptr[B1 + t + 1];
    float a[8] = {0, 0, 0, 0, 0, 0, 0, 0};
    pull8(s, e, ebuf, (const char*)f1u_ui + q, a);
    uint4 sv = *reinterpret_cast<const uint4*>((const char*)f1i_ui + (size_t)t * 128 + q);
    float v[8] = {0, 0, 0, 0, 0, 0, 0, 0};
    addbf8(sv, v);
    float s1 = 0.f, s2 = 0.f;
#pragma unroll
    for (int k = 0; k < 8; k++) { s1 = fmaf(v[k], v[k], s1); s2 = fmaf(a[k], a[k], s2); }
    s1 = rowsum8(s1);
    s2 = rowsum8(s2);
    float i1 = 1.0f / fmaxf(sqrtf(s1), 1e-12f);
    float i2 = 1.0f / fmaxf(sqrtf(s2), 1e-12f);
    const float4 b0 = *reinterpret_cast<const float4*>(I + (size_t)t * D + l * 8);
    const float4 b1 = *reinterpret_cast<const float4*>(I + (size_t)t * D + l * 8 + 4);
    float o[8];
    o[0] = b0.x + v[0] * i1 + a[0] * i2;
    o[1] = b0.y + v[1] * i1 + a[1] * i2;
    o[2] = b0.z + v[2] * i1 + a[2] * i2;
    o[3] = b0.w + v[3] * i1 + a[3] * i2;
    o[4] = b1.x + v[4] * i1 + a[4] * i2;
    o[5] = b1.y + v[5] * i1 + a[5] * i2;
    o[6] = b1.z + v[6] * i1 + a[6] * i2;
    o[7] = b1.w + v[7] * i1 + a[7] * i2;
    *reinterpret_cast<uint4*>((char*)f1i_ui + (size_t)t * 128 + q) = pack8(o);
}

// stage3: weighted bi aggregation from bf16 acc_i -> outB[:,0:64] (f32)
__global__ void stage3_k(const int* __restrict__ rowptr, const int* __restrict__ ebuf,
                         const ushort_t* __restrict__ acc_i, float* __restrict__ outB) {
    int t = blockIdx.x * 32 + (threadIdx.x >> 3);
    if (t >= NB) return;
    int l = threadIdx.x & 7;
    int q = l << 4;
    int s = rowptr[B4 + t], e = rowptr[B4 + t + 1];
    float a[8] = {0, 0, 0, 0, 0, 0, 0, 0};
    pull8(s, e, ebuf, (const char*)acc_i + q, a);
    float w = 1.0f / ((float)(e - s) + 1e-8f);
    float4 o0 = {a[0] * w, a[1] * w, a[2] * w, a[3] * w};
    float4 o1 = {a[4] * w, a[5] * w, a[6] * w, a[7] * w};
    *reinterpret_cast<float4*>(outB + (size_t)t * 128 + l * 8) = o0;
    *reinterpret_cast<float4*>(outB + (size_t)t * 128 + l * 8 + 4) = o1;
}

extern "C" void kernel_launch(void* const* d_in, const int* in_sizes, int n_in,
                              void* d_out, int out_size, void* d_ws, size_t ws_size,
                              hipStream_t stream) {
    const float* U = (const float*)d_in[0];
    const float* I = (const float*)d_in[1];
    const float* B = (const float*)d_in[2];
    const int* ui_row = (const int*)d_in[3];
    const int* ui_col = (const int*)d_in[4];
    const int* ub_row = (const int*)d_in[5];
    const int* ub_col = (const int*)d_in[6];
    const int* bi_row = (const int*)d_in[7];
    const int* bi_col = (const int*)d_in[8];
    const int E_UI = in_sizes[3], E_UB = in_sizes[5], E_BI = in_sizes[7];
    const int ETOT = 2 * E_UI + 2 * E_UB + E_BI;

    // workspace layout (~144 MB): bf16 tables + bf16 intermediates + CSR
    ushort_t* Ubh    = (ushort_t*)d_ws;                 // NU*D
    ushort_t* Ibh    = Ubh + (size_t)NU * D;            // NI*D
    ushort_t* Bbh    = Ibh + (size_t)NI * D;            // NB*D
    ushort_t* f1u_ui = Bbh + (size_t)NB * D;            // NU*D
    ushort_t* f1i_ui = f1u_ui + (size_t)NU * D;         // NI*D (becomes acc_i)
    ushort_t* f1u_ub = f1i_ui + (size_t)NI * D;         // NU*D
    ushort_t* f1b_ub = f1u_ub + (size_t)NU * D;         // NB*D
    int* rowptr    = (int*)(f1b_ub + (size_t)NB * D);   // RTOT+1
    int* gcur      = rowptr + (RTOT + 1);               // NBKT_PAD (512)
    int* gbase     = gcur + NBKT_PAD;                   // NBKT_PAD (512, uses NBKT+1)
    int* ebuf      = gbase + NBKT_PAD;                  // ETOT
    int* bbuf      = ebuf + ETOT;                       // ETOT

    float* outU = (float*)d_out;            // NU x 128 (IL_u | BL_u)
    float* outB = outU + (size_t)NU * 128;  // NB x 128 (IL_b | BL_b)

    const int T = 256;
    const int NCVT = (NU + NI + NB) * D / 8;

    // ---- bf16 table conversion ----
    cvt_all_k<<<(NCVT + T - 1) / T, T, 0, stream>>>(U, I, B, Ubh, Ibh, Bbh);

    // ---- bucket-level CSR build ----
    hipMemsetAsync(gbase, 0, NBKT_PAD * sizeof(int), stream);
    bhist_k<<<1280, T, 0, stream>>>(ui_row, ui_col, ub_row, ub_col, bi_row,
                                    E_UI, E_UB, E_BI, ETOT, gbase);
    bscan_k<<<1, 64, 0, stream>>>(gbase, gcur, rowptr);

    // ---- edge binning (binB also derives per-row rowptr locally) ----
    binA_k<<<(ETOT + TILE - 1) / TILE, 256, 0, stream>>>(ui_row, ui_col, ub_row, ub_col,
                                                         bi_row, bi_col, E_UI, E_UB, E_BI,
                                                         ETOT, gcur, bbuf);
    binB_k<<<NBKT, 1024, 0, stream>>>(gbase, bbuf, rowptr, ebuf);

    // ---- stage1: all four layer-1 pulls ----
    stage1_k<<<(B4 + 31) / 32, T, 0, stream>>>(rowptr, ebuf, Ubh, Ibh, Bbh,
                                               f1u_ui, f1i_ui, f1u_ub, f1b_ub);
    // ---- stage2a: ui-user, ub-user, ub-bundle finalize ----
    stage2a_k<<<(2 * NU + NB + 31) / 32, T, 0, stream>>>(rowptr, ebuf, U, B,
                                                         f1u_ui, f1i_ui, f1u_ub, f1b_ub,
                                                         outU, outB);
    // ---- stage2b: ui-item finalize (in-place bf16 acc_i) ----
    stage2b_k<<<(NI + 31) / 32, T, 0, stream>>>(rowptr, ebuf, I, f1u_ui, f1i_ui);
    // ---- stage3: weighted bi aggregation ----
    stage3_k<<<(NB + 31) / 32, T, 0, stream>>>(rowptr, ebuf, f1i_ui, outB);
}

// Round 15
// 435.012 us; speedup vs baseline: 1.5257x; 1.0499x over previous
//
#include <hip/hip_runtime.h>
#include <hip/hip_bf16.h>

// Problem constants (match reference setup_inputs)
#define NU 100000
#define NI 200000
#define NB 50000
#define D  64

// Concatenated CSR row-space: 5 graph directions
#define B0 0
#define B1 (NU)
#define B2 (NU + NI)
#define B3 (2 * NU + NI)
#define B4 (2 * NU + NI + NB)
#define RTOT (2 * NU + NI + 2 * NB)   // 500000 rows total

// Bucketing for the two-phase edge sort
// BKT_SHIFT=10: 489 buckets -> binB grid covers all 256 CUs.
#define BKT_SHIFT 10
#define ROWS_PER_BKT 1024
#define NBKT ((RTOT + ROWS_PER_BKT - 1) / ROWS_PER_BKT)   // 489
#define NBKT_PAD 512
#define TILE 4096
#define EPT (TILE / 256)

typedef unsigned short ushort_t;

// ======================= bf16 helpers =======================

__device__ __forceinline__ unsigned f2bf(float f) {
    unsigned u = __float_as_uint(f);
    return (u + 0x7FFFu + ((u >> 16) & 1u)) >> 16;   // RNE
}

__device__ __forceinline__ uint4 pack8(const float* a) {
    uint4 o;
    o.x = f2bf(a[0]) | (f2bf(a[1]) << 16);
    o.y = f2bf(a[2]) | (f2bf(a[3]) << 16);
    o.z = f2bf(a[4]) | (f2bf(a[5]) << 16);
    o.w = f2bf(a[6]) | (f2bf(a[7]) << 16);
    return o;
}

__device__ __forceinline__ void addbf8(uint4 v, float* a) {
    a[0] += __uint_as_float(v.x << 16);
    a[1] += __uint_as_float(v.x & 0xFFFF0000u);
    a[2] += __uint_as_float(v.y << 16);
    a[3] += __uint_as_float(v.y & 0xFFFF0000u);
    a[4] += __uint_as_float(v.z << 16);
    a[5] += __uint_as_float(v.z & 0xFFFF0000u);
    a[6] += __uint_as_float(v.w << 16);
    a[7] += __uint_as_float(v.w & 0xFFFF0000u);
}

// f32 tables -> bf16 tables (one fused launch; 8 elems/thread).
// Block 0 also zeroes gbase (folds the memset dispatch).
__global__ void cvt_all_k(const float* __restrict__ U, const float* __restrict__ I,
                          const float* __restrict__ Bf,
                          ushort_t* __restrict__ Ubh, ushort_t* __restrict__ Ibh,
                          ushort_t* __restrict__ Bbh, int* __restrict__ gbase) {
    if (blockIdx.x == 0 && threadIdx.x < 256) {
        gbase[threadIdx.x] = 0;
        gbase[256 + threadIdx.x] = 0;
    }
    int t = blockIdx.x * blockDim.x + threadIdx.x;
    const int nU = NU * D / 8, nI = NI * D / 8, nB = NB * D / 8;
    const float* s; ushort_t* d;
    if (t < nU)           { s = U;  d = Ubh; }
    else if (t < nU + nI) { s = I;  d = Ibh; t -= nU; }
    else if (t < nU + nI + nB) { s = Bf; d = Bbh; t -= nU + nI; }
    else return;
    const float4 f0 = *reinterpret_cast<const float4*>(s + (size_t)t * 8);
    const float4 f1 = *reinterpret_cast<const float4*>(s + (size_t)t * 8 + 4);
    float a[8] = {f0.x, f0.y, f0.z, f0.w, f1.x, f1.y, f1.z, f1.w};
    *reinterpret_cast<uint4*>(d + (size_t)t * 8) = pack8(a);
}

// ======================= bucket histogram =======================

__global__ __launch_bounds__(256) void bhist_k(
        const int* __restrict__ ui_row, const int* __restrict__ ui_col,
        const int* __restrict__ ub_row, const int* __restrict__ ub_col,
        const int* __restrict__ bi_row,
        int E_UI, int E_UB, int E_BI, int ETOT, int* __restrict__ gbase) {
    __shared__ int h[NBKT];
    int tid = threadIdx.x;
    for (int b = tid; b < NBKT; b += 256) h[b] = 0;
    __syncthreads();
    for (int i = blockIdx.x * 256 + tid; i < ETOT; i += gridDim.x * 256) {
        int gdst;
        if (i < E_UI)                     gdst = B0 + ui_row[i];
        else if (i < 2 * E_UI)            gdst = B1 + ui_col[i - E_UI];
        else if (i < 2 * E_UI + E_UB)     gdst = B2 + ub_row[i - 2 * E_UI];
        else if (i < 2 * E_UI + 2 * E_UB) gdst = B3 + ub_col[i - 2 * E_UI - E_UB];
        else                              gdst = B4 + bi_row[i - 2 * E_UI - 2 * E_UB];
        atomicAdd(&h[gdst >> BKT_SHIFT], 1);
    }
    __syncthreads();
    for (int b = tid; b < NBKT; b += 256)
        if (h[b]) atomicAdd(&gbase[b], h[b]);
}

// one-wave exclusive scan of the 489 bucket counts -> gbase (bases), gcur copy.
__global__ void bscan_k(int* __restrict__ gbase, int* __restrict__ gcur,
                        int* __restrict__ rowptr) {
    int lane = threadIdx.x;  // 64
    int vals[8];
    int s = 0;
#pragma unroll
    for (int k = 0; k < 8; k++) {
        int id = lane * 8 + k;
        vals[k] = (id < NBKT) ? gbase[id] : 0;
        s += vals[k];
    }
    int x = s;
#pragma unroll
    for (int off = 1; off < 64; off <<= 1) {
        int y = __shfl_up(x, off, 64);
        if (lane >= off) x += y;
    }
    int excl = x - s;
#pragma unroll
    for (int k = 0; k < 8; k++) {
        int id = lane * 8 + k;
        if (id <= NBKT) { gbase[id] = excl; if (id < NBKT) gcur[id] = excl; }
        excl += vals[k];
    }
    if (lane == 63) rowptr[RTOT] = x;   // total == ETOT
}

// ======================= edge binning =======================

__device__ __forceinline__ void decode_edge(int i,
        const int* __restrict__ ui_row, const int* __restrict__ ui_col,
        const int* __restrict__ ub_row, const int* __restrict__ ub_col,
        const int* __restrict__ bi_row, const int* __restrict__ bi_col,
        int E_UI, int E_UB, int E_BI, int& gdst, int& src) {
    if (i < E_UI)                     { gdst = B0 + ui_row[i]; src = ui_col[i]; }
    else if (i < 2 * E_UI)            { int j = i - E_UI; gdst = B1 + ui_col[j]; src = ui_row[j]; }
    else if (i < 2 * E_UI + E_UB)     { int j = i - 2 * E_UI; gdst = B2 + ub_row[j]; src = ub_col[j]; }
    else if (i < 2 * E_UI + 2 * E_UB) { int j = i - 2 * E_UI - E_UB; gdst = B3 + ub_col[j]; src = ub_row[j]; }
    else                              { int j = i - 2 * E_UI - 2 * E_UB; gdst = B4 + bi_row[j]; src = bi_col[j]; }
}

// Phase A: tile-local counting sort by coarse bucket; bbuf entry: (src<<10)|(gdst&1023)
// Edges decoded ONCE into registers; bucket scan wave-parallel (489 buckets).
__global__ __launch_bounds__(256) void binA_k(
        const int* __restrict__ ui_row, const int* __restrict__ ui_col,
        const int* __restrict__ ub_row, const int* __restrict__ ub_col,
        const int* __restrict__ bi_row, const int* __restrict__ bi_col,
        int E_UI, int E_UB, int E_BI, int ETOT,
        int* __restrict__ gcur, int* __restrict__ bbuf) {
    __shared__ int hist[NBKT], runStart[NBKT], gbase[NBKT], cnt2[NBKT];
    __shared__ int ord[TILE];
    __shared__ int gpos[TILE];
    int tid = threadIdx.x;
    for (int b = tid; b < NBKT; b += 256) { hist[b] = 0; cnt2[b] = 0; }
    __syncthreads();
    int base = blockIdx.x * TILE;
    int gd[EPT], sr[EPT];
#pragma unroll
    for (int k = 0; k < EPT; k++) {
        int i = base + k * 256 + tid;
        gd[k] = -1;
        if (i < ETOT) {
            decode_edge(i, ui_row, ui_col, ub_row, ub_col, bi_row, bi_col,
                        E_UI, E_UB, E_BI, gd[k], sr[k]);
            atomicAdd(&hist[gd[k] >> BKT_SHIFT], 1);
        }
    }
    __syncthreads();
    // wave-parallel exclusive scan of hist -> runStart (first 64 threads)
    if (tid < 64) {
        int vals[8];
        int ssum = 0;
#pragma unroll
        for (int k = 0; k < 8; k++) {
            int id = tid * 8 + k;
            vals[k] = (id < NBKT) ? hist[id] : 0;
            ssum += vals[k];
        }
        int x = ssum;
#pragma unroll
        for (int off = 1; off < 64; off <<= 1) {
            int y = __shfl_up(x, off, 64);
            if (tid >= off) x += y;
        }
        int excl = x - ssum;
#pragma unroll
        for (int k = 0; k < 8; k++) {
            int id = tid * 8 + k;
            if (id < NBKT) runStart[id] = excl;
            excl += vals[k];
        }
    }
    __syncthreads();
    for (int b = tid; b < NBKT; b += 256)
        if (hist[b] > 0) gbase[b] = atomicAdd(&gcur[b], hist[b]);
    __syncthreads();
#pragma unroll
    for (int k = 0; k < EPT; k++) {
        if (gd[k] >= 0) {
            int b = gd[k] >> BKT_SHIFT;
            int loc = runStart[b] + atomicAdd(&cnt2[b], 1);
            ord[loc] = (sr[k] << BKT_SHIFT) | (gd[k] & (ROWS_PER_BKT - 1));
            gpos[loc] = gbase[b] + (loc - runStart[b]);
        }
    }
    __syncthreads();
    int tcnt = runStart[NBKT - 1] + hist[NBKT - 1];
    for (int i = tid; i < tcnt; i += 256) bbuf[gpos[i]] = ord[i];
}

// Phase B: per-bucket row degree histogram + local scan -> writes rowptr AND
// places edges. 489 blocks x 1024 threads.
__global__ __launch_bounds__(1024) void binB_k(const int* __restrict__ gbase,
                                               const int* __restrict__ bbuf,
                                               int* __restrict__ rowptr,
                                               int* __restrict__ ebuf) {
    __shared__ int lh[ROWS_PER_BKT];   // histogram -> exclusive offsets -> cursors
    __shared__ int ws[16];
    int bkt = blockIdx.x;
    int tid = threadIdx.x;
    int s = gbase[bkt], e = gbase[bkt + 1];
    int rbase = bkt << BKT_SHIFT;
    int nrows = RTOT - rbase;
    if (nrows > ROWS_PER_BKT) nrows = ROWS_PER_BKT;
    lh[tid] = 0;
    __syncthreads();
    // pass 1: local degree histogram
    for (int i = s + tid; i < e; i += 1024)
        atomicAdd(&lh[bbuf[i] & (ROWS_PER_BKT - 1)], 1);
    __syncthreads();
    // block exclusive scan of 1024 entries (1 per thread)
    int v = lh[tid];
    int lane = tid & 63, w = tid >> 6;
    int x = v;
#pragma unroll
    for (int off = 1; off < 64; off <<= 1) {
        int y = __shfl_up(x, off, 64);
        if (lane >= off) x += y;
    }
    if (lane == 63) ws[w] = x;
    __syncthreads();
    if (tid == 0) {
        int run = 0;
#pragma unroll
        for (int k = 0; k < 16; k++) { int t = ws[k]; ws[k] = run; run += t; }
    }
    __syncthreads();
    int p = s + ws[w] + (x - v);   // exclusive offset for row tid
    lh[tid] = p;
    if (tid < nrows) rowptr[rbase + tid] = p;
    __syncthreads();
    // pass 2: place edges
    for (int i = s + tid; i < e; i += 1024) {
        int entry = bbuf[i];
        int r = entry & (ROWS_PER_BKT - 1);
        int pos = atomicAdd(&lh[r], 1);
        ebuf[pos] = (entry >> BKT_SHIFT) << 7;
    }
}

// ======================= pull machinery (bf16, 8 lanes/row) =======================
// wave = 8 rows; lane l: group = l>>3 (row), q = (l&7)*16B (8 dims as bf16x8).

__device__ __forceinline__ void pull8(int s, int e, const int* __restrict__ ebuf,
                                      const char* __restrict__ baseq, float* a) {
    int j = s;
    for (; j + 7 < e; j += 8) {
        int c0 = ebuf[j],     c1 = ebuf[j + 1], c2 = ebuf[j + 2], c3 = ebuf[j + 3];
        int c4 = ebuf[j + 4], c5 = ebuf[j + 5], c6 = ebuf[j + 6], c7 = ebuf[j + 7];
        uint4 v0 = *reinterpret_cast<const uint4*>(baseq + c0);
        uint4 v1 = *reinterpret_cast<const uint4*>(baseq + c1);
        uint4 v2 = *reinterpret_cast<const uint4*>(baseq + c2);
        uint4 v3 = *reinterpret_cast<const uint4*>(baseq + c3);
        uint4 v4 = *reinterpret_cast<const uint4*>(baseq + c4);
        uint4 v5 = *reinterpret_cast<const uint4*>(baseq + c5);
        uint4 v6 = *reinterpret_cast<const uint4*>(baseq + c6);
        uint4 v7 = *reinterpret_cast<const uint4*>(baseq + c7);
        addbf8(v0, a); addbf8(v1, a); addbf8(v2, a); addbf8(v3, a);
        addbf8(v4, a); addbf8(v5, a); addbf8(v6, a); addbf8(v7, a);
    }
    for (; j + 3 < e; j += 4) {
        int c0 = ebuf[j], c1 = ebuf[j + 1], c2 = ebuf[j + 2], c3 = ebuf[j + 3];
        uint4 v0 = *reinterpret_cast<const uint4*>(baseq + c0);
        uint4 v1 = *reinterpret_cast<const uint4*>(baseq + c1);
        uint4 v2 = *reinterpret_cast<const uint4*>(baseq + c2);
        uint4 v3 = *reinterpret_cast<const uint4*>(baseq + c3);
        addbf8(v0, a); addbf8(v1, a); addbf8(v2, a); addbf8(v3, a);
    }
    for (; j < e; ++j) {
        uint4 v = *reinterpret_cast<const uint4*>(baseq + ebuf[j]);
        addbf8(v, a);
    }
}

__device__ __forceinline__ float rowsum8(float s) {
    s += __shfl_xor(s, 1, 64);
    s += __shfl_xor(s, 2, 64);
    s += __shfl_xor(s, 4, 64);
    return s;
}

// stage1: all four layer-1 pulls fused; bf16 in, bf16 out, no cross-lane needed
__global__ void stage1_k(const int* __restrict__ rowptr, const int* __restrict__ ebuf,
                         const ushort_t* __restrict__ Ubh, const ushort_t* __restrict__ Ibh,
                         const ushort_t* __restrict__ Bbh,
                         ushort_t* __restrict__ f1u_ui, ushort_t* __restrict__ f1i_ui,
                         ushort_t* __restrict__ f1u_ub, ushort_t* __restrict__ f1b_ub) {
    int gr = blockIdx.x * 32 + (threadIdx.x >> 3);
    if (gr >= B4) return;
    int q = (threadIdx.x & 7) << 4;
    const ushort_t* src; ushort_t* dst; int row;
    if (gr < B1)      { src = Ibh; dst = f1u_ui; row = gr; }
    else if (gr < B2) { src = Ubh; dst = f1i_ui; row = gr - B1; }
    else if (gr < B3) { src = Bbh; dst = f1u_ub; row = gr - B2; }
    else              { src = Ubh; dst = f1b_ub; row = gr - B3; }
    int s = rowptr[gr], e = rowptr[gr + 1];
    float a[8] = {0, 0, 0, 0, 0, 0, 0, 0};
    pull8(s, e, ebuf, (const char*)src + q, a);
    *reinterpret_cast<uint4*>((char*)dst + (size_t)row * 128 + q) = pack8(a);
}

// finalize: out(f32) = base + l2norm(self) + l2norm(acc)
__device__ __forceinline__ void fin8_f32(const float* a, const ushort_t* selfbh,
                                         const float* basef, float* out, int row, int l) {
    int q = l << 4;
    uint4 sv = *reinterpret_cast<const uint4*>((const char*)selfbh + (size_t)row * 128 + q);
    float v[8] = {0, 0, 0, 0, 0, 0, 0, 0};
    addbf8(sv, v);
    float s1 = 0.f, s2 = 0.f;
#pragma unroll
    for (int k = 0; k < 8; k++) { s1 = fmaf(v[k], v[k], s1); s2 = fmaf(a[k], a[k], s2); }
    s1 = rowsum8(s1);
    s2 = rowsum8(s2);
    float i1 = 1.0f / fmaxf(sqrtf(s1), 1e-12f);
    float i2 = 1.0f / fmaxf(sqrtf(s2), 1e-12f);
    const float4 b0 = *reinterpret_cast<const float4*>(basef + (size_t)row * D + l * 8);
    const float4 b1 = *reinterpret_cast<const float4*>(basef + (size_t)row * D + l * 8 + 4);
    float4 o0, o1;
    o0.x = b0.x + v[0] * i1 + a[0] * i2;
    o0.y = b0.y + v[1] * i1 + a[1] * i2;
    o0.z = b0.z + v[2] * i1 + a[2] * i2;
    o0.w = b0.w + v[3] * i1 + a[3] * i2;
    o1.x = b1.x + v[4] * i1 + a[4] * i2;
    o1.y = b1.y + v[5] * i1 + a[5] * i2;
    o1.z = b1.z + v[6] * i1 + a[6] * i2;
    o1.w = b1.w + v[7] * i1 + a[7] * i2;
    *reinterpret_cast<float4*>(out + (size_t)row * 128 + l * 8) = o0;
    *reinterpret_cast<float4*>(out + (size_t)row * 128 + l * 8 + 4) = o1;
}

// stage23: fused stage2a (ui-user, ub-user, ub-bundle finalize -> f32 outputs)
// and stage2b (ui-item finalize -> acc_i). stage2b writes acc_i into Ibh
// (dead after stage1) instead of in-place over f1i_ui -- f1i_ui is read
// concurrently by the 2a path, so in-place would race.
__global__ void stage23_k(const int* __restrict__ rowptr, const int* __restrict__ ebuf,
                          const float* __restrict__ U, const float* __restrict__ Bf,
                          const float* __restrict__ I,
                          const ushort_t* __restrict__ f1u_ui, const ushort_t* __restrict__ f1i_ui,
                          const ushort_t* __restrict__ f1u_ub, const ushort_t* __restrict__ f1b_ub,
                          ushort_t* __restrict__ acc_i,
                          float* __restrict__ outU, float* __restrict__ outB) {
    int t = blockIdx.x * 32 + (threadIdx.x >> 3);
    if (t >= 2 * NU + NB + NI) return;
    int l = threadIdx.x & 7;
    int q = l << 4;
    if (t < 2 * NU + NB) {
        // ---- stage2a path ----
        int cr, row; const ushort_t* src; const ushort_t* self; const float* basef; float* out;
        if (t < NU)          { cr = t;               src = f1i_ui; self = f1u_ui; basef = U;  out = outU;      row = t; }
        else if (t < 2 * NU) { cr = B2 + t - NU;     src = f1b_ub; self = f1u_ub; basef = U;  out = outU + 64; row = t - NU; }
        else                 { cr = B3 + t - 2 * NU; src = f1u_ub; self = f1b_ub; basef = Bf; out = outB + 64; row = t - 2 * NU; }
        int s = rowptr[cr], e = rowptr[cr + 1];
        float a[8] = {0, 0, 0, 0, 0, 0, 0, 0};
        pull8(s, e, ebuf, (const char*)src + q, a);
        fin8_f32(a, self, basef, out, row, l);
    } else {
        // ---- stage2b path: ui-item finalize -> acc_i (bf16, in Ibh) ----
        int row = t - (2 * NU + NB);
        int s = rowptr[B1 + row], e = rowptr[B1 + row + 1];
        float a[8] = {0, 0, 0, 0, 0, 0, 0, 0};
        pull8(s, e, ebuf, (const char*)f1u_ui + q, a);
        uint4 sv = *reinterpret_cast<const uint4*>((const char*)f1i_ui + (size_t)row * 128 + q);
        float v[8] = {0, 0, 0, 0, 0, 0, 0, 0};
        addbf8(sv, v);
        float s1 = 0.f, s2 = 0.f;
#pragma unroll
        for (int k = 0; k < 8; k++) { s1 = fmaf(v[k], v[k], s1); s2 = fmaf(a[k], a[k], s2); }
        s1 = rowsum8(s1);
        s2 = rowsum8(s2);
        float i1 = 1.0f / fmaxf(sqrtf(s1), 1e-12f);
        float i2 = 1.0f / fmaxf(sqrtf(s2), 1e-12f);
        const float4 b0 = *reinterpret_cast<const float4*>(I + (size_t)row * D + l * 8);
        const float4 b1 = *reinterpret_cast<const float4*>(I + (size_t)row * D + l * 8 + 4);
        float o[8];
        o[0] = b0.x + v[0] * i1 + a[0] * i2;
        o[1] = b0.y + v[1] * i1 + a[1] * i2;
        o[2] = b0.z + v[2] * i1 + a[2] * i2;
        o[3] = b0.w + v[3] * i1 + a[3] * i2;
        o[4] = b1.x + v[4] * i1 + a[4] * i2;
        o[5] = b1.y + v[5] * i1 + a[5] * i2;
        o[6] = b1.z + v[6] * i1 + a[6] * i2;
        o[7] = b1.w + v[7] * i1 + a[7] * i2;
        *reinterpret_cast<uint4*>((char*)acc_i + (size_t)row * 128 + q) = pack8(o);
    }
}

// stage3: weighted bi aggregation from bf16 acc_i -> outB[:,0:64] (f32)
__global__ void stage3_k(const int* __restrict__ rowptr, const int* __restrict__ ebuf,
                         const ushort_t* __restrict__ acc_i, float* __restrict__ outB) {
    int t = blockIdx.x * 32 + (threadIdx.x >> 3);
    if (t >= NB) return;
    int l = threadIdx.x & 7;
    int q = l << 4;
    int s = rowptr[B4 + t], e = rowptr[B4 + t + 1];
    float a[8] = {0, 0, 0, 0, 0, 0, 0, 0};
    pull8(s, e, ebuf, (const char*)acc_i + q, a);
    float w = 1.0f / ((float)(e - s) + 1e-8f);
    float4 o0 = {a[0] * w, a[1] * w, a[2] * w, a[3] * w};
    float4 o1 = {a[4] * w, a[5] * w, a[6] * w, a[7] * w};
    *reinterpret_cast<float4*>(outB + (size_t)t * 128 + l * 8) = o0;
    *reinterpret_cast<float4*>(outB + (size_t)t * 128 + l * 8 + 4) = o1;
}

extern "C" void kernel_launch(void* const* d_in, const int* in_sizes, int n_in,
                              void* d_out, int out_size, void* d_ws, size_t ws_size,
                              hipStream_t stream) {
    const float* U = (const float*)d_in[0];
    const float* I = (const float*)d_in[1];
    const float* B = (const float*)d_in[2];
    const int* ui_row = (const int*)d_in[3];
    const int* ui_col = (const int*)d_in[4];
    const int* ub_row = (const int*)d_in[5];
    const int* ub_col = (const int*)d_in[6];
    const int* bi_row = (const int*)d_in[7];
    const int* bi_col = (const int*)d_in[8];
    const int E_UI = in_sizes[3], E_UB = in_sizes[5], E_BI = in_sizes[7];
    const int ETOT = 2 * E_UI + 2 * E_UB + E_BI;

    // workspace layout (~144 MB): bf16 tables + bf16 intermediates + CSR
    ushort_t* Ubh    = (ushort_t*)d_ws;                 // NU*D
    ushort_t* Ibh    = Ubh + (size_t)NU * D;            // NI*D (becomes acc_i in stage23)
    ushort_t* Bbh    = Ibh + (size_t)NI * D;            // NB*D
    ushort_t* f1u_ui = Bbh + (size_t)NB * D;            // NU*D
    ushort_t* f1i_ui = f1u_ui + (size_t)NU * D;         // NI*D
    ushort_t* f1u_ub = f1i_ui + (size_t)NI * D;         // NU*D
    ushort_t* f1b_ub = f1u_ub + (size_t)NU * D;         // NB*D
    int* rowptr    = (int*)(f1b_ub + (size_t)NB * D);   // RTOT+1
    int* gcur      = rowptr + (RTOT + 1);               // NBKT_PAD (512)
    int* gbase     = gcur + NBKT_PAD;                   // NBKT_PAD (512, uses NBKT+1)
    int* ebuf      = gbase + NBKT_PAD;                  // ETOT
    int* bbuf      = ebuf + ETOT;                       // ETOT

    float* outU = (float*)d_out;            // NU x 128 (IL_u | BL_u)
    float* outB = outU + (size_t)NU * 128;  // NB x 128 (IL_b | BL_b)

    const int T = 256;
    const int NCVT = (NU + NI + NB) * D / 8;

    // ---- bf16 table conversion (also zeroes gbase) ----
    cvt_all_k<<<(NCVT + T - 1) / T, T, 0, stream>>>(U, I, B, Ubh, Ibh, Bbh, gbase);

    // ---- bucket-level CSR build ----
    bhist_k<<<512, T, 0, stream>>>(ui_row, ui_col, ub_row, ub_col, bi_row,
                                   E_UI, E_UB, E_BI, ETOT, gbase);
    bscan_k<<<1, 64, 0, stream>>>(gbase, gcur, rowptr);

    // ---- edge binning (binB also derives per-row rowptr locally) ----
    binA_k<<<(ETOT + TILE - 1) / TILE, 256, 0, stream>>>(ui_row, ui_col, ub_row, ub_col,
                                                         bi_row, bi_col, E_UI, E_UB, E_BI,
                                                         ETOT, gcur, bbuf);
    binB_k<<<NBKT, 1024, 0, stream>>>(gbase, bbuf, rowptr, ebuf);

    // ---- stage1: all four layer-1 pulls ----
    stage1_k<<<(B4 + 31) / 32, T, 0, stream>>>(rowptr, ebuf, Ubh, Ibh, Bbh,
                                               f1u_ui, f1i_ui, f1u_ub, f1b_ub);
    // ---- stage23: fused finalize (2a -> outputs; 2b -> acc_i in Ibh) ----
    stage23_k<<<(2 * NU + NB + NI + 31) / 32, T, 0, stream>>>(rowptr, ebuf, U, B, I,
                                                              f1u_ui, f1i_ui, f1u_ub, f1b_ub,
                                                              Ibh, outU, outB);
    // ---- stage3: weighted bi aggregation ----
    stage3_k<<<(NB + 31) / 32, T, 0, stream>>>(rowptr, ebuf, Ibh, outB);
}

// Round 17
// 433.005 us; speedup vs baseline: 1.5328x; 1.0046x over previous
//
#include <hip/hip_runtime.h>
#include <hip/hip_bf16.h>

// Problem constants (match reference setup_inputs)
#define NU 100000
#define NI 200000
#define NB 50000
#define D  64

// Concatenated CSR row-space: 5 graph directions
#define B0 0
#define B1 (NU)
#define B2 (NU + NI)
#define B3 (2 * NU + NI)
#define B4 (2 * NU + NI + NB)
#define RTOT (2 * NU + NI + 2 * NB)   // 500000 rows total

// Bucketing for the two-phase edge sort
// BKT_SHIFT=10: 489 buckets -> binB grid covers all 256 CUs.
#define BKT_SHIFT 10
#define ROWS_PER_BKT 1024
#define NBKT ((RTOT + ROWS_PER_BKT - 1) / ROWS_PER_BKT)   // 489
#define NBKT_PAD 512
// binA: 8192-edge tiles, 512 threads (2x write-run length vs 4096/256,
// same 16 waves/CU occupancy: 71.6KB LDS x 2 blocks/CU)
#define TILE 8192
#define ABLK 512
#define EPT (TILE / ABLK)   // 16

// bhist part of init_k
#define HBLK 512

typedef unsigned short ushort_t;

// ======================= bf16 helpers =======================

__device__ __forceinline__ unsigned f2bf(float f) {
    unsigned u = __float_as_uint(f);
    return (u + 0x7FFFu + ((u >> 16) & 1u)) >> 16;   // RNE
}

__device__ __forceinline__ uint4 pack8(const float* a) {
    uint4 o;
    o.x = f2bf(a[0]) | (f2bf(a[1]) << 16);
    o.y = f2bf(a[2]) | (f2bf(a[3]) << 16);
    o.z = f2bf(a[4]) | (f2bf(a[5]) << 16);
    o.w = f2bf(a[6]) | (f2bf(a[7]) << 16);
    return o;
}

__device__ __forceinline__ void addbf8(uint4 v, float* a) {
    a[0] += __uint_as_float(v.x << 16);
    a[1] += __uint_as_float(v.x & 0xFFFF0000u);
    a[2] += __uint_as_float(v.y << 16);
    a[3] += __uint_as_float(v.y & 0xFFFF0000u);
    a[4] += __uint_as_float(v.z << 16);
    a[5] += __uint_as_float(v.z & 0xFFFF0000u);
    a[6] += __uint_as_float(v.w << 16);
    a[7] += __uint_as_float(v.w & 0xFFFF0000u);
}

// ======================= init: bf16 conversion + bucket histogram fused ====
// Blocks [0, nCvt): f32->bf16 table conversion (streaming, 112 MB).
// Blocks [nCvt, nCvt+HBLK): LDS-staged 489-bucket edge histogram (20 MB).
// Independent workloads overlap in one dispatch. gbase zeroed by a prior
// stream-ordered memset (cannot zero in-kernel: histogram blocks may run first).
__global__ __launch_bounds__(256) void init_k(
        const float* __restrict__ U, const float* __restrict__ I,
        const float* __restrict__ Bf,
        ushort_t* __restrict__ Ubh, ushort_t* __restrict__ Ibh,
        ushort_t* __restrict__ Bbh,
        const int* __restrict__ ui_row, const int* __restrict__ ui_col,
        const int* __restrict__ ub_row, const int* __restrict__ ub_col,
        const int* __restrict__ bi_row,
        int E_UI, int E_UB, int E_BI, int ETOT, int nCvt,
        int* __restrict__ gbase) {
    if ((int)blockIdx.x >= nCvt) {
        __shared__ int h[NBKT];
        int tid = threadIdx.x;
        for (int b = tid; b < NBKT; b += 256) h[b] = 0;
        __syncthreads();
        int gb = blockIdx.x - nCvt;
        for (int i = gb * 256 + tid; i < ETOT; i += HBLK * 256) {
            int gdst;
            if (i < E_UI)                     gdst = B0 + ui_row[i];
            else if (i < 2 * E_UI)            gdst = B1 + ui_col[i - E_UI];
            else if (i < 2 * E_UI + E_UB)     gdst = B2 + ub_row[i - 2 * E_UI];
            else if (i < 2 * E_UI + 2 * E_UB) gdst = B3 + ub_col[i - 2 * E_UI - E_UB];
            else                              gdst = B4 + bi_row[i - 2 * E_UI - 2 * E_UB];
            atomicAdd(&h[gdst >> BKT_SHIFT], 1);
        }
        __syncthreads();
        for (int b = tid; b < NBKT; b += 256)
            if (h[b]) atomicAdd(&gbase[b], h[b]);
        return;
    }
    int t = blockIdx.x * blockDim.x + threadIdx.x;
    const int nU = NU * D / 8, nI = NI * D / 8, nB = NB * D / 8;
    const float* s; ushort_t* d;
    if (t < nU)           { s = U;  d = Ubh; }
    else if (t < nU + nI) { s = I;  d = Ibh; t -= nU; }
    else if (t < nU + nI + nB) { s = Bf; d = Bbh; t -= nU + nI; }
    else return;
    const float4 f0 = *reinterpret_cast<const float4*>(s + (size_t)t * 8);
    const float4 f1 = *reinterpret_cast<const float4*>(s + (size_t)t * 8 + 4);
    float a[8] = {f0.x, f0.y, f0.z, f0.w, f1.x, f1.y, f1.z, f1.w};
    *reinterpret_cast<uint4*>(d + (size_t)t * 8) = pack8(a);
}

// one-wave exclusive scan of the 489 bucket counts -> gbase (bases), gcur copy.
__global__ void bscan_k(int* __restrict__ gbase, int* __restrict__ gcur,
                        int* __restrict__ rowptr) {
    int lane = threadIdx.x;  // 64
    int vals[8];
    int s = 0;
#pragma unroll
    for (int k = 0; k < 8; k++) {
        int id = lane * 8 + k;
        vals[k] = (id < NBKT) ? gbase[id] : 0;
        s += vals[k];
    }
    int x = s;
#pragma unroll
    for (int off = 1; off < 64; off <<= 1) {
        int y = __shfl_up(x, off, 64);
        if (lane >= off) x += y;
    }
    int excl = x - s;
#pragma unroll
    for (int k = 0; k < 8; k++) {
        int id = lane * 8 + k;
        if (id <= NBKT) { gbase[id] = excl; if (id < NBKT) gcur[id] = excl; }
        excl += vals[k];
    }
    if (lane == 63) rowptr[RTOT] = x;   // total == ETOT
}

// ======================= edge binning =======================

__device__ __forceinline__ void decode_edge(int i,
        const int* __restrict__ ui_row, const int* __restrict__ ui_col,
        const int* __restrict__ ub_row, const int* __restrict__ ub_col,
        const int* __restrict__ bi_row, const int* __restrict__ bi_col,
        int E_UI, int E_UB, int E_BI, int& gdst, int& src) {
    if (i < E_UI)                     { gdst = B0 + ui_row[i]; src = ui_col[i]; }
    else if (i < 2 * E_UI)            { int j = i - E_UI; gdst = B1 + ui_col[j]; src = ui_row[j]; }
    else if (i < 2 * E_UI + E_UB)     { int j = i - 2 * E_UI; gdst = B2 + ub_row[j]; src = ub_col[j]; }
    else if (i < 2 * E_UI + 2 * E_UB) { int j = i - 2 * E_UI - E_UB; gdst = B3 + ub_col[j]; src = ub_row[j]; }
    else                              { int j = i - 2 * E_UI - 2 * E_UB; gdst = B4 + bi_row[j]; src = bi_col[j]; }
}

// Phase A: tile-local counting sort by coarse bucket; bbuf entry: (src<<10)|(gdst&1023)
// 8192-edge tiles, 512 threads; edges decoded ONCE into registers.
__global__ __launch_bounds__(ABLK) void binA_k(
        const int* __restrict__ ui_row, const int* __restrict__ ui_col,
        const int* __restrict__ ub_row, const int* __restrict__ ub_col,
        const int* __restrict__ bi_row, const int* __restrict__ bi_col,
        int E_UI, int E_UB, int E_BI, int ETOT,
        int* __restrict__ gcur, int* __restrict__ bbuf) {
    __shared__ int hist[NBKT], runStart[NBKT], gbase[NBKT], cnt2[NBKT];
    __shared__ int ord[TILE];
    __shared__ int gpos[TILE];
    int tid = threadIdx.x;
    for (int b = tid; b < NBKT; b += ABLK) { hist[b] = 0; cnt2[b] = 0; }
    __syncthreads();
    int base = blockIdx.x * TILE;
    int gd[EPT], sr[EPT];
#pragma unroll
    for (int k = 0; k < EPT; k++) {
        int i = base + k * ABLK + tid;
        gd[k] = -1;
        if (i < ETOT) {
            decode_edge(i, ui_row, ui_col, ub_row, ub_col, bi_row, bi_col,
                        E_UI, E_UB, E_BI, gd[k], sr[k]);
            atomicAdd(&hist[gd[k] >> BKT_SHIFT], 1);
        }
    }
    __syncthreads();
    // wave-parallel exclusive scan of hist -> runStart (first 64 threads)
    if (tid < 64) {
        int vals[8];
        int ssum = 0;
#pragma unroll
        for (int k = 0; k < 8; k++) {
            int id = tid * 8 + k;
            vals[k] = (id < NBKT) ? hist[id] : 0;
            ssum += vals[k];
        }
        int x = ssum;
#pragma unroll
        for (int off = 1; off < 64; off <<= 1) {
            int y = __shfl_up(x, off, 64);
            if (tid >= off) x += y;
        }
        int excl = x - ssum;
#pragma unroll
        for (int k = 0; k < 8; k++) {
            int id = tid * 8 + k;
            if (id < NBKT) runStart[id] = excl;
            excl += vals[k];
        }
    }
    __syncthreads();
    for (int b = tid; b < NBKT; b += ABLK)
        if (hist[b] > 0) gbase[b] = atomicAdd(&gcur[b], hist[b]);
    __syncthreads();
#pragma unroll
    for (int k = 0; k < EPT; k++) {
        if (gd[k] >= 0) {
            int b = gd[k] >> BKT_SHIFT;
            int loc = runStart[b] + atomicAdd(&cnt2[b], 1);
            ord[loc] = (sr[k] << BKT_SHIFT) | (gd[k] & (ROWS_PER_BKT - 1));
            gpos[loc] = gbase[b] + (loc - runStart[b]);
        }
    }
    __syncthreads();
    int tcnt = runStart[NBKT - 1] + hist[NBKT - 1];
    for (int i = tid; i < tcnt; i += ABLK) bbuf[gpos[i]] = ord[i];
}

// Phase B: per-bucket row degree histogram + local scan -> writes rowptr AND
// places edges. 489 blocks x 1024 threads.
__global__ __launch_bounds__(1024) void binB_k(const int* __restrict__ gbase,
                                               const int* __restrict__ bbuf,
                                               int* __restrict__ rowptr,
                                               int* __restrict__ ebuf) {
    __shared__ int lh[ROWS_PER_BKT];   // histogram -> exclusive offsets -> cursors
    __shared__ int ws[16];
    int bkt = blockIdx.x;
    int tid = threadIdx.x;
    int s = gbase[bkt], e = gbase[bkt + 1];
    int rbase = bkt << BKT_SHIFT;
    int nrows = RTOT - rbase;
    if (nrows > ROWS_PER_BKT) nrows = ROWS_PER_BKT;
    lh[tid] = 0;
    __syncthreads();
    // pass 1: local degree histogram
    for (int i = s + tid; i < e; i += 1024)
        atomicAdd(&lh[bbuf[i] & (ROWS_PER_BKT - 1)], 1);
    __syncthreads();
    // block exclusive scan of 1024 entries (1 per thread)
    int v = lh[tid];
    int lane = tid & 63, w = tid >> 6;
    int x = v;
#pragma unroll
    for (int off = 1; off < 64; off <<= 1) {
        int y = __shfl_up(x, off, 64);
        if (lane >= off) x += y;
    }
    if (lane == 63) ws[w] = x;
    __syncthreads();
    if (tid == 0) {
        int run = 0;
#pragma unroll
        for (int k = 0; k < 16; k++) { int t = ws[k]; ws[k] = run; run += t; }
    }
    __syncthreads();
    int p = s + ws[w] + (x - v);   // exclusive offset for row tid
    lh[tid] = p;
    if (tid < nrows) rowptr[rbase + tid] = p;
    __syncthreads();
    // pass 2: place edges
    for (int i = s + tid; i < e; i += 1024) {
        int entry = bbuf[i];
        int r = entry & (ROWS_PER_BKT - 1);
        int pos = atomicAdd(&lh[r], 1);
        ebuf[pos] = (entry >> BKT_SHIFT) << 7;
    }
}

// ======================= pull machinery (bf16, 8 lanes/row) =======================
// wave = 8 rows; lane l: group = l>>3 (row), q = (l&7)*16B (8 dims as bf16x8).

__device__ __forceinline__ void pull8(int s, int e, const int* __restrict__ ebuf,
                                      const char* __restrict__ baseq, float* a) {
    int j = s;
    for (; j + 7 < e; j += 8) {
        int c0 = ebuf[j],     c1 = ebuf[j + 1], c2 = ebuf[j + 2], c3 = ebuf[j + 3];
        int c4 = ebuf[j + 4], c5 = ebuf[j + 5], c6 = ebuf[j + 6], c7 = ebuf[j + 7];
        uint4 v0 = *reinterpret_cast<const uint4*>(baseq + c0);
        uint4 v1 = *reinterpret_cast<const uint4*>(baseq + c1);
        uint4 v2 = *reinterpret_cast<const uint4*>(baseq + c2);
        uint4 v3 = *reinterpret_cast<const uint4*>(baseq + c3);
        uint4 v4 = *reinterpret_cast<const uint4*>(baseq + c4);
        uint4 v5 = *reinterpret_cast<const uint4*>(baseq + c5);
        uint4 v6 = *reinterpret_cast<const uint4*>(baseq + c6);
        uint4 v7 = *reinterpret_cast<const uint4*>(baseq + c7);
        addbf8(v0, a); addbf8(v1, a); addbf8(v2, a); addbf8(v3, a);
        addbf8(v4, a); addbf8(v5, a); addbf8(v6, a); addbf8(v7, a);
    }
    for (; j + 3 < e; j += 4) {
        int c0 = ebuf[j], c1 = ebuf[j + 1], c2 = ebuf[j + 2], c3 = ebuf[j + 3];
        uint4 v0 = *reinterpret_cast<const uint4*>(baseq + c0);
        uint4 v1 = *reinterpret_cast<const uint4*>(baseq + c1);
        uint4 v2 = *reinterpret_cast<const uint4*>(baseq + c2);
        uint4 v3 = *reinterpret_cast<const uint4*>(baseq + c3);
        addbf8(v0, a); addbf8(v1, a); addbf8(v2, a); addbf8(v3, a);
    }
    for (; j < e; ++j) {
        uint4 v = *reinterpret_cast<const uint4*>(baseq + ebuf[j]);
        addbf8(v, a);
    }
}

__device__ __forceinline__ float rowsum8(float s) {
    s += __shfl_xor(s, 1, 64);
    s += __shfl_xor(s, 2, 64);
    s += __shfl_xor(s, 4, 64);
    return s;
}

// stage1: all four layer-1 pulls fused; bf16 in, bf16 out, no cross-lane needed
__global__ void stage1_k(const int* __restrict__ rowptr, const int* __restrict__ ebuf,
                         const ushort_t* __restrict__ Ubh, const ushort_t* __restrict__ Ibh,
                         const ushort_t* __restrict__ Bbh,
                         ushort_t* __restrict__ f1u_ui, ushort_t* __restrict__ f1i_ui,
                         ushort_t* __restrict__ f1u_ub, ushort_t* __restrict__ f1b_ub) {
    int gr = blockIdx.x * 32 + (threadIdx.x >> 3);
    if (gr >= B4) return;
    int q = (threadIdx.x & 7) << 4;
    const ushort_t* src; ushort_t* dst; int row;
    if (gr < B1)      { src = Ibh; dst = f1u_ui; row = gr; }
    else if (gr < B2) { src = Ubh; dst = f1i_ui; row = gr - B1; }
    else if (gr < B3) { src = Bbh; dst = f1u_ub; row = gr - B2; }
    else              { src = Ubh; dst = f1b_ub; row = gr - B3; }
    int s = rowptr[gr], e = rowptr[gr + 1];
    float a[8] = {0, 0, 0, 0, 0, 0, 0, 0};
    pull8(s, e, ebuf, (const char*)src + q, a);
    *reinterpret_cast<uint4*>((char*)dst + (size_t)row * 128 + q) = pack8(a);
}

// finalize: out(f32) = base + l2norm(self) + l2norm(acc)
__device__ __forceinline__ void fin8_f32(const float* a, const ushort_t* selfbh,
                                         const float* basef, float* out, int row, int l) {
    int q = l << 4;
    uint4 sv = *reinterpret_cast<const uint4*>((const char*)selfbh + (size_t)row * 128 + q);
    float v[8] = {0, 0, 0, 0, 0, 0, 0, 0};
    addbf8(sv, v);
    float s1 = 0.f, s2 = 0.f;
#pragma unroll
    for (int k = 0; k < 8; k++) { s1 = fmaf(v[k], v[k], s1); s2 = fmaf(a[k], a[k], s2); }
    s1 = rowsum8(s1);
    s2 = rowsum8(s2);
    float i1 = 1.0f / fmaxf(sqrtf(s1), 1e-12f);
    float i2 = 1.0f / fmaxf(sqrtf(s2), 1e-12f);
    const float4 b0 = *reinterpret_cast<const float4*>(basef + (size_t)row * D + l * 8);
    const float4 b1 = *reinterpret_cast<const float4*>(basef + (size_t)row * D + l * 8 + 4);
    float4 o0, o1;
    o0.x = b0.x + v[0] * i1 + a[0] * i2;
    o0.y = b0.y + v[1] * i1 + a[1] * i2;
    o0.z = b0.z + v[2] * i1 + a[2] * i2;
    o0.w = b0.w + v[3] * i1 + a[3] * i2;
    o1.x = b1.x + v[4] * i1 + a[4] * i2;
    o1.y = b1.y + v[5] * i1 + a[5] * i2;
    o1.z = b1.z + v[6] * i1 + a[6] * i2;
    o1.w = b1.w + v[7] * i1 + a[7] * i2;
    *reinterpret_cast<float4*>(out + (size_t)row * 128 + l * 8) = o0;
    *reinterpret_cast<float4*>(out + (size_t)row * 128 + l * 8 + 4) = o1;
}

// stage23: fused stage2a (ui-user, ub-user, ub-bundle finalize -> f32 outputs)
// and stage2b (ui-item finalize -> acc_i). stage2b writes acc_i into Ibh
// (dead after stage1) instead of in-place over f1i_ui -- f1i_ui is read
// concurrently by the 2a path, so in-place would race.
__global__ void stage23_k(const int* __restrict__ rowptr, const int* __restrict__ ebuf,
                          const float* __restrict__ U, const float* __restrict__ Bf,
                          const float* __restrict__ I,
                          const ushort_t* __restrict__ f1u_ui, const ushort_t* __restrict__ f1i_ui,
                          const ushort_t* __restrict__ f1u_ub, const ushort_t* __restrict__ f1b_ub,
                          ushort_t* __restrict__ acc_i,
                          float* __restrict__ outU, float* __restrict__ outB) {
    int t = blockIdx.x * 32 + (threadIdx.x >> 3);
    if (t >= 2 * NU + NB + NI) return;
    int l = threadIdx.x & 7;
    int q = l << 4;
    if (t < 2 * NU + NB) {
        // ---- stage2a path ----
        int cr, row; const ushort_t* src; const ushort_t* self; const float* basef; float* out;
        if (t < NU)          { cr = t;               src = f1i_ui; self = f1u_ui; basef = U;  out = outU;      row = t; }
        else if (t < 2 * NU) { cr = B2 + t - NU;     src = f1b_ub; self = f1u_ub; basef = U;  out = outU + 64; row = t - NU; }
        else                 { cr = B3 + t - 2 * NU; src = f1u_ub; self = f1b_ub; basef = Bf; out = outB + 64; row = t - 2 * NU; }
        int s = rowptr[cr], e = rowptr[cr + 1];
        float a[8] = {0, 0, 0, 0, 0, 0, 0, 0};
        pull8(s, e, ebuf, (const char*)src + q, a);
        fin8_f32(a, self, basef, out, row, l);
    } else {
        // ---- stage2b path: ui-item finalize -> acc_i (bf16, in Ibh) ----
        int row = t - (2 * NU + NB);
        int s = rowptr[B1 + row], e = rowptr[B1 + row + 1];
        float a[8] = {0, 0, 0, 0, 0, 0, 0, 0};
        pull8(s, e, ebuf, (const char*)f1u_ui + q, a);
        uint4 sv = *reinterpret_cast<const uint4*>((const char*)f1i_ui + (size_t)row * 128 + q);
        float v[8] = {0, 0, 0, 0, 0, 0, 0, 0};
        addbf8(sv, v);
        float s1 = 0.f, s2 = 0.f;
#pragma unroll
        for (int k = 0; k < 8; k++) { s1 = fmaf(v[k], v[k], s1); s2 = fmaf(a[k], a[k], s2); }
        s1 = rowsum8(s1);
        s2 = rowsum8(s2);
        float i1 = 1.0f / fmaxf(sqrtf(s1), 1e-12f);
        float i2 = 1.0f / fmaxf(sqrtf(s2), 1e-12f);
        const float4 b0 = *reinterpret_cast<const float4*>(I + (size_t)row * D + l * 8);
        const float4 b1 = *reinterpret_cast<const float4*>(I + (size_t)row * D + l * 8 + 4);
        float o[8];
        o[0] = b0.x + v[0] * i1 + a[0] * i2;
        o[1] = b0.y + v[1] * i1 + a[1] * i2;
        o[2] = b0.z + v[2] * i1 + a[2] * i2;
        o[3] = b0.w + v[3] * i1 + a[3] * i2;
        o[4] = b1.x + v[4] * i1 + a[4] * i2;
        o[5] = b1.y + v[5] * i1 + a[5] * i2;
        o[6] = b1.z + v[6] * i1 + a[6] * i2;
        o[7] = b1.w + v[7] * i1 + a[7] * i2;
        *reinterpret_cast<uint4*>((char*)acc_i + (size_t)row * 128 + q) = pack8(o);
    }
}

// stage3: weighted bi aggregation from bf16 acc_i -> outB[:,0:64] (f32)
__global__ void stage3_k(const int* __restrict__ rowptr, const int* __restrict__ ebuf,
                         const ushort_t* __restrict__ acc_i, float* __restrict__ outB) {
    int t = blockIdx.x * 32 + (threadIdx.x >> 3);
    if (t >= NB) return;
    int l = threadIdx.x & 7;
    int q = l << 4;
    int s = rowptr[B4 + t], e = rowptr[B4 + t + 1];
    float a[8] = {0, 0, 0, 0, 0, 0, 0, 0};
    pull8(s, e, ebuf, (const char*)acc_i + q, a);
    float w = 1.0f / ((float)(e - s) + 1e-8f);
    float4 o0 = {a[0] * w, a[1] * w, a[2] * w, a[3] * w};
    float4 o1 = {a[4] * w, a[5] * w, a[6] * w, a[7] * w};
    *reinterpret_cast<float4*>(outB + (size_t)t * 128 + l * 8) = o0;
    *reinterpret_cast<float4*>(outB + (size_t)t * 128 + l * 8 + 4) = o1;
}

extern "C" void kernel_launch(void* const* d_in, const int* in_sizes, int n_in,
                              void* d_out, int out_size, void* d_ws, size_t ws_size,
                              hipStream_t stream) {
    const float* U = (const float*)d_in[0];
    const float* I = (const float*)d_in[1];
    const float* B = (const float*)d_in[2];
    const int* ui_row = (const int*)d_in[3];
    const int* ui_col = (const int*)d_in[4];
    const int* ub_row = (const int*)d_in[5];
    const int* ub_col = (const int*)d_in[6];
    const int* bi_row = (const int*)d_in[7];
    const int* bi_col = (const int*)d_in[8];
    const int E_UI = in_sizes[3], E_UB = in_sizes[5], E_BI = in_sizes[7];
    const int ETOT = 2 * E_UI + 2 * E_UB + E_BI;

    // workspace layout (~144 MB): bf16 tables + bf16 intermediates + CSR
    ushort_t* Ubh    = (ushort_t*)d_ws;                 // NU*D
    ushort_t* Ibh    = Ubh + (size_t)NU * D;            // NI*D (becomes acc_i in stage23)
    ushort_t* Bbh    = Ibh + (size_t)NI * D;            // NB*D
    ushort_t* f1u_ui = Bbh + (size_t)NB * D;            // NU*D
    ushort_t* f1i_ui = f1u_ui + (size_t)NU * D;         // NI*D
    ushort_t* f1u_ub = f1i_ui + (size_t)NI * D;         // NU*D
    ushort_t* f1b_ub = f1u_ub + (size_t)NU * D;         // NB*D
    int* rowptr    = (int*)(f1b_ub + (size_t)NB * D);   // RTOT+1
    int* gcur      = rowptr + (RTOT + 1);               // NBKT_PAD (512)
    int* gbase     = gcur + NBKT_PAD;                   // NBKT_PAD (512, uses NBKT+1)
    int* ebuf      = gbase + NBKT_PAD;                  // ETOT
    int* bbuf      = ebuf + ETOT;                       // ETOT

    float* outU = (float*)d_out;            // NU x 128 (IL_u | BL_u)
    float* outB = outU + (size_t)NU * 128;  // NB x 128 (IL_b | BL_b)

    const int T = 256;
    const int NCVT = (NU + NI + NB) * D / 8;
    const int nCvtBlocks = (NCVT + T - 1) / T;

    // ---- init: bf16 conversion + bucket histogram (fused, overlapped) ----
    hipMemsetAsync(gbase, 0, NBKT_PAD * sizeof(int), stream);
    init_k<<<nCvtBlocks + HBLK, T, 0, stream>>>(U, I, B, Ubh, Ibh, Bbh,
                                                ui_row, ui_col, ub_row, ub_col, bi_row,
                                                E_UI, E_UB, E_BI, ETOT, nCvtBlocks, gbase);
    bscan_k<<<1, 64, 0, stream>>>(gbase, gcur, rowptr);

    // ---- edge binning (binB also derives per-row rowptr locally) ----
    binA_k<<<(ETOT + TILE - 1) / TILE, ABLK, 0, stream>>>(ui_row, ui_col, ub_row, ub_col,
                                                          bi_row, bi_col, E_UI, E_UB, E_BI,
                                                          ETOT, gcur, bbuf);
    binB_k<<<NBKT, 1024, 0, stream>>>(gbase, bbuf, rowptr, ebuf);

    // ---- stage1: all four layer-1 pulls ----
    stage1_k<<<(B4 + 31) / 32, T, 0, stream>>>(rowptr, ebuf, Ubh, Ibh, Bbh,
                                               f1u_ui, f1i_ui, f1u_ub, f1b_ub);
    // ---- stage23: fused finalize (2a -> outputs; 2b -> acc_i in Ibh) ----
    stage23_k<<<(2 * NU + NB + NI + 31) / 32, T, 0, stream>>>(rowptr, ebuf, U, B, I,
                                                              f1u_ui, f1i_ui, f1u_ub, f1b_ub,
                                                              Ibh, outU, outB);
    // ---- stage3: weighted bi aggregation ----
    stage3_k<<<(NB + 31) / 32, T, 0, stream>>>(rowptr, ebuf, Ibh, outB);
}